// Round 7
// baseline (715.185 us; speedup 1.0000x reference)
//
#include <hip/hip_runtime.h>
#include <hip/hip_bf16.h>

typedef __attribute__((ext_vector_type(8))) short short8;
typedef __attribute__((ext_vector_type(4))) float f32x4;

__device__ __forceinline__ unsigned bf16u(float x) {
    unsigned u = __float_as_uint(x);
    return (u + 0x7fffu + ((u >> 16) & 1u)) >> 16;
}
__device__ __forceinline__ short bf16s(float x) { return (short)bf16u(x); }

// ---------------------------------------------------------------------------
// Prep: pack Wm1 (8x64), Wm2 (64x64), Wm3 (64x320) into MFMA B-fragment
// layout (bf16). Frag (t,kh): lane l holds B[k=kh*32+(l>>4)*8+i][col=16t+(l&15)].
// ---------------------------------------------------------------------------
__global__ __launch_bounds__(256) void prep_kernel(
    const float* __restrict__ Wm1, const float* __restrict__ Wm2,
    const float* __restrict__ Wm3,
    short* __restrict__ W1B, short* __restrict__ Wm2B, short* __restrict__ W3B)
{
    int idx = blockIdx.x * 256 + threadIdx.x;   // 52 frags * 64 lanes
    if (idx >= 52 * 64) return;
    int l = idx & 63, f = idx >> 6;
    int g = l >> 4, c = l & 15;
    short8 v;
    if (f < 4) {                 // W1B tile t=f: k=i (g==0 only), col=16f+c
        #pragma unroll
        for (int i = 0; i < 8; ++i)
            v[i] = (g == 0) ? bf16s(Wm1[(size_t)i * 64 + f * 16 + c]) : (short)0;
        *(short8*)(W1B + (size_t)f * 512 + l * 8) = v;
    } else if (f < 12) {         // Wm2B
        int f2 = f - 4, t = f2 >> 1, kh = f2 & 1;
        #pragma unroll
        for (int i = 0; i < 8; ++i)
            v[i] = bf16s(Wm2[(size_t)(kh * 32 + g * 8 + i) * 64 + t * 16 + c]);
        *(short8*)(Wm2B + (size_t)f2 * 512 + l * 8) = v;
    } else {                     // W3B
        int f3 = f - 12, t = f3 >> 1, kh = f3 & 1;
        #pragma unroll
        for (int i = 0; i < 8; ++i)
            v[i] = bf16s(Wm3[(size_t)(kh * 32 + g * 8 + i) * 320 + t * 16 + c]);
        *(short8*)(W3B + (size_t)f3 * 512 + l * 8) = v;
    }
}

// ---------------------------------------------------------------------------
// CSR build: histogram -> 3-phase parallel scan -> bucket fill (+ pack)
// ---------------------------------------------------------------------------
__global__ __launch_bounds__(256) void hist_kernel(
    const int* __restrict__ receivers, int* __restrict__ cnt, int E)
{
    int i = blockIdx.x * 256 + threadIdx.x;
    int stride = gridDim.x * 256;
    for (; i < E; i += stride) atomicAdd(&cnt[receivers[i]], 1);
}

// scan1: each block scans 1024 elements (4/thread), writes local-exclusive
// results to offs and block total to part[b].
__global__ __launch_bounds__(256) void scan1_kernel(
    const int* __restrict__ cnt, int* __restrict__ offs,
    int* __restrict__ part, int N)
{
    __shared__ int a_[256], b_[256];
    const int b = blockIdx.x, t = threadIdx.x;
    const int base = b * 1024 + t * 4;
    int v[4];
    #pragma unroll
    for (int k = 0; k < 4; ++k) v[k] = (base + k < N) ? cnt[base + k] : 0;
    int sum = v[0] + v[1] + v[2] + v[3];
    a_[t] = sum;
    __syncthreads();
    int* src = a_; int* dst = b_;
    for (int off = 1; off < 256; off <<= 1) {
        dst[t] = src[t] + ((t >= off) ? src[t - off] : 0);
        __syncthreads();
        int* tmp = src; src = dst; dst = tmp;
    }
    int excl = src[t] - sum;
    if (t == 0) part[b] = src[255];
    int run = excl;
    #pragma unroll
    for (int k = 0; k < 4; ++k) {
        if (base + k < N) offs[base + k] = run;
        run += v[k];
    }
}

// scan2: serial exclusive scan of block partials (nblk <= ~256), total -> offs[N]
__global__ void scan2_kernel(int* __restrict__ part, int* __restrict__ offs,
                             int nblk, int N)
{
    if (threadIdx.x == 0 && blockIdx.x == 0) {
        int running = 0;
        for (int i = 0; i < nblk; ++i) {
            int tmp = part[i];
            part[i] = running;
            running += tmp;
        }
        offs[N] = running;
    }
}

// scan3: add block base to offs, mirror into cursor
__global__ __launch_bounds__(256) void scan3_kernel(
    int* __restrict__ offs, int* __restrict__ cursor,
    const int* __restrict__ part, int N)
{
    const int b = blockIdx.x, t = threadIdx.x;
    const int add = part[b];
    const int base = b * 1024 + t * 4;
    #pragma unroll
    for (int k = 0; k < 4; ++k) {
        int i = base + k;
        if (i < N) {
            int o = offs[i] + add;
            offs[i] = o;
            cursor[i] = o;
        }
    }
}

// Scatter per-edge packed record into CSR position:
//  epackA[pos] = basis[0..7] bf16 pairs (MFMA A-fragment data)
//  epackB[pos] = { Yx, Yy, Yz, sender_bits }
__global__ __launch_bounds__(256) void fill_pack_kernel(
    const float* __restrict__ vectors, const int* __restrict__ senders,
    const int* __restrict__ receivers, int* __restrict__ cursor,
    uint4* __restrict__ epackA, float4* __restrict__ epackB, int E)
{
    int i = blockIdx.x * 256 + threadIdx.x;
    int stride = gridDim.x * 256;
    for (; i < E; i += stride) {
        int pos = atomicAdd(&cursor[receivers[i]], 1);
        float vx = vectors[3 * (size_t)i + 0];
        float vy = vectors[3 * (size_t)i + 1];
        float vz = vectors[3 * (size_t)i + 2];
        float r = sqrtf(vx * vx + vy * vy + vz * vz);
        float ir = (r != 0.f) ? 1.f / r : 0.f;
        float ang = r * 0.6283185307179586f;   // pi/5
        float s1, c1;
        __sincosf(ang, &s1, &c1);
        float tc = 2.f * c1;
        float sb = s1, sp = 0.f;
        float coef = 0.6324555320336759f * ir;
        unsigned bw[4];
        #pragma unroll
        for (int h = 0; h < 4; ++h) {
            unsigned lo = bf16u(sb * coef);
            float nx = tc * sb - sp; sp = sb; sb = nx;
            unsigned hi = bf16u(sb * coef);
            nx = tc * sb - sp; sp = sb; sb = nx;
            bw[h] = lo | (hi << 16);
        }
        epackA[pos] = make_uint4(bw[0], bw[1], bw[2], bw[3]);
        epackB[pos] = make_float4(vx * ir, vy * ir, vz * ir,
                                  __int_as_float(senders[i]));
    }
}

// ---------------------------------------------------------------------------
// Node up-projection, d-major interleaved output:
// u[n*256 + d*4 + comp], comp 0..3 = {u0, u1x, u1y, u1z}[d]
// -> per-(edge,q) gather in edge_kernel is one float4 per lane, 256B/line-run.
// ---------------------------------------------------------------------------
__global__ __launch_bounds__(256) void node_up_kernel(
    const float* __restrict__ node_feats, const float* __restrict__ W0_up,
    const float* __restrict__ W1_up, float* __restrict__ u)
{
    int n = blockIdx.x;
    int t = threadIdx.x;
    const float* nf = node_feats + (size_t)n * 256;
    int comp = t >> 6, d = t & 63;
    float f = 0.f;
    if (comp == 0) {
        #pragma unroll 8
        for (int c = 0; c < 64; ++c) f += nf[c] * W0_up[c * 64 + d];
    } else {
        int i = comp - 1;
        #pragma unroll 8
        for (int c = 0; c < 64; ++c) f += nf[64 + c * 3 + i] * W1_up[c * 64 + d];
    }
    u[(size_t)n * 256 + d * 4 + comp] = f;
}

// ---------------------------------------------------------------------------
// Edge kernel v7: wave per receiver node, 16-edge MFMA chunks.
//  - u gathered as d-major float4: one dwordx4/lane, full-line consumption
//  - W3B fragments staged in LDS; ping-pong pipelined q loop
// ---------------------------------------------------------------------------
__global__ __launch_bounds__(256, 3) void edge_kernel(
    const uint4* __restrict__ epackA, const float4* __restrict__ epackB,
    const int* __restrict__ offs, const float4* __restrict__ u4,
    const short* __restrict__ W1B, const short* __restrict__ Wm2B,
    const short* __restrict__ W3B, float* __restrict__ acc, int N)
{
    __shared__ __align__(16) short ldsW3[40 * 512];   // 40KB staged W3B
    __shared__ __align__(16) short ldsH[4][1024];     // per-wave h buffer (swz)
    __shared__ __align__(16) float ldsMeta[4][16][4]; // Y.xyz + sender

    {   // cooperative stage of W3B (2560 short8)
        const short8* src = (const short8*)W3B;
        short8* dst = (short8*)ldsW3;
        for (int i = threadIdx.x; i < 2560; i += 256) dst[i] = src[i];
    }
    __syncthreads();

    const int lane = threadIdx.x & 63;
    const int wv   = threadIdx.x >> 6;
    const int n    = blockIdx.x * 4 + wv;
    if (n >= N) return;
    const int c = lane & 15, g = lane >> 4;

    float a0q[4]  = {0.f, 0.f, 0.f, 0.f};
    float a1xq[4] = {0.f, 0.f, 0.f, 0.f};
    float a1yq[4] = {0.f, 0.f, 0.f, 0.f};
    float a1zq[4] = {0.f, 0.f, 0.f, 0.f};

    const int beg = offs[n], end = offs[n + 1];

    for (int p0 = beg; p0 < end; p0 += 16) {
        const int m = end - p0;

        // ---- prologue: lanes 0-15, one packed record each ----
        short8 basisA = {0, 0, 0, 0, 0, 0, 0, 0};
        if (lane < 16) {
            uint4 ba = epackA[p0 + lane];
            float4 mb = epackB[p0 + lane];
            if (lane >= m) {
                ba = make_uint4(0u, 0u, 0u, 0u);
                mb = make_float4(0.f, 0.f, 0.f, __int_as_float(0));
            }
            union { uint4 u4v; short8 s8; } cv;
            cv.u4v = ba;
            basisA = cv.s8;
            *(float4*)&ldsMeta[wv][lane][0] = mb;
        }

        // ---- per-lane edge meta for its 4 rows ----
        float Yx[4], Yy[4], Yz[4];
        int snd[4];
        #pragma unroll
        for (int i = 0; i < 4; ++i) {
            int row = 4 * g + i;
            float4 mt = *(const float4*)&ldsMeta[wv][row][0];
            Yx[i] = mt.x; Yy[i] = mt.y; Yz[i] = mt.z;
            snd[i] = __float_as_int(mt.w);
        }

#define PFETCH(Q, M0, M1X, M1Y, M1Z)                                        \
        _Pragma("unroll")                                                   \
        for (int i = 0; i < 4; ++i) {                                       \
            float4 mv = u4[(size_t)snd[i] * 64 + 16 * (Q) + c];             \
            M0[i]  = mv.x; M1X[i] = mv.y;                                   \
            M1Y[i] = mv.z; M1Z[i] = mv.w;                                   \
        }

#define COMPQ(Q, M0, M1X, M1Y, M1Z)                                         \
        _Pragma("unroll")                                                   \
        for (int p = 0; p < 5; ++p) {                                       \
            const int t = 4 * p + (Q);                                      \
            f32x4 w = {0.f, 0.f, 0.f, 0.f};                                 \
            short8 b0 = *(const short8*)(ldsW3 + (size_t)(t * 2) * 512 + lane * 8);     \
            short8 b1 = *(const short8*)(ldsW3 + (size_t)(t * 2 + 1) * 512 + lane * 8); \
            w = __builtin_amdgcn_mfma_f32_16x16x32_bf16(h2f0, b0, w, 0, 0, 0);          \
            w = __builtin_amdgcn_mfma_f32_16x16x32_bf16(h2f1, b1, w, 0, 0, 0);          \
            _Pragma("unroll")                                               \
            for (int i = 0; i < 4; ++i) {                                   \
                float wv_ = w[i];                                           \
                if (p == 0) {                                               \
                    a0q[Q] += wv_ * M0[i];                                  \
                } else if (p == 1) {                                        \
                    float tt = wv_ * M0[i];                                 \
                    a1xq[Q] += tt * Yx[i];                                  \
                    a1yq[Q] += tt * Yy[i];                                  \
                    a1zq[Q] += tt * Yz[i];                                  \
                } else if (p == 2) {                                        \
                    a1xq[Q] += wv_ * M1X[i];                                \
                    a1yq[Q] += wv_ * M1Y[i];                                \
                    a1zq[Q] += wv_ * M1Z[i];                                \
                } else if (p == 3) {                                        \
                    a0q[Q] += wv_ * (M1X[i] * Yx[i] + M1Y[i] * Yy[i] + M1Z[i] * Yz[i]); \
                } else {                                                    \
                    a1xq[Q] += wv_ * (M1Y[i] * Yz[i] - M1Z[i] * Yy[i]);     \
                    a1yq[Q] += wv_ * (M1Z[i] * Yx[i] - M1X[i] * Yz[i]);     \
                    a1zq[Q] += wv_ * (M1X[i] * Yy[i] - M1Y[i] * Yx[i]);     \
                }                                                           \
            }                                                               \
        }

        float m0A[4], m1xA[4], m1yA[4], m1zA[4];
        float m0B[4], m1xB[4], m1yB[4], m1zB[4];
        PFETCH(0, m0A, m1xA, m1yA, m1zA);
        PFETCH(1, m0B, m1xB, m1yB, m1zB);
        __builtin_amdgcn_sched_barrier(0);   // keep gathers issued here

        // ---- layer 1: 4 MFMAs; silu -> ldsH (swizzled bf16) ----
        #pragma unroll
        for (int t = 0; t < 4; ++t) {
            f32x4 h = {0.f, 0.f, 0.f, 0.f};
            short8 bf = *(const short8*)(W1B + (size_t)t * 512 + lane * 8);
            h = __builtin_amdgcn_mfma_f32_16x16x32_bf16(basisA, bf, h, 0, 0, 0);
            #pragma unroll
            for (int i = 0; i < 4; ++i) {
                float x = h[i];
                float h1 = x / (1.f + __expf(-x));
                int row = 4 * g + i;
                ldsH[wv][row * 64 + ((16 * t + c) ^ ((row & 7) << 3))] = bf16s(h1);
            }
        }
        short8 h1f0 = *(const short8*)&ldsH[wv][c * 64 + ((g * 8) ^ ((c & 7) << 3))];
        short8 h1f1 = *(const short8*)&ldsH[wv][c * 64 + ((32 + g * 8) ^ ((c & 7) << 3))];

        // ---- layer 2: 8 MFMAs; silu -> ldsH (reuse) ----
        #pragma unroll
        for (int t = 0; t < 4; ++t) {
            f32x4 h = {0.f, 0.f, 0.f, 0.f};
            short8 b0 = *(const short8*)(Wm2B + (size_t)(t * 2) * 512 + lane * 8);
            short8 b1 = *(const short8*)(Wm2B + (size_t)(t * 2 + 1) * 512 + lane * 8);
            h = __builtin_amdgcn_mfma_f32_16x16x32_bf16(h1f0, b0, h, 0, 0, 0);
            h = __builtin_amdgcn_mfma_f32_16x16x32_bf16(h1f1, b1, h, 0, 0, 0);
            #pragma unroll
            for (int i = 0; i < 4; ++i) {
                float x = h[i];
                float h2 = x / (1.f + __expf(-x));
                int row = 4 * g + i;
                ldsH[wv][row * 64 + ((16 * t + c) ^ ((row & 7) << 3))] = bf16s(h2);
            }
        }
        short8 h2f0 = *(const short8*)&ldsH[wv][c * 64 + ((g * 8) ^ ((c & 7) << 3))];
        short8 h2f1 = *(const short8*)&ldsH[wv][c * 64 + ((32 + g * 8) ^ ((c & 7) << 3))];

        // ---- layer 3 + fused messages, ping-pong pipelined over q ----
        COMPQ(0, m0A, m1xA, m1yA, m1zA);
        __builtin_amdgcn_sched_barrier(0);
        PFETCH(2, m0A, m1xA, m1yA, m1zA);
        COMPQ(1, m0B, m1xB, m1yB, m1zB);
        __builtin_amdgcn_sched_barrier(0);
        PFETCH(3, m0B, m1xB, m1yB, m1zB);
        COMPQ(2, m0A, m1xA, m1yA, m1zA);
        __builtin_amdgcn_sched_barrier(0);
        COMPQ(3, m0B, m1xB, m1yB, m1zB);
#undef PFETCH
#undef COMPQ
    }

    // ---- reduce across the 4 g-groups and store ----
    #pragma unroll
    for (int q = 0; q < 4; ++q) {
        a0q[q]  += __shfl_xor(a0q[q], 16);  a0q[q]  += __shfl_xor(a0q[q], 32);
        a1xq[q] += __shfl_xor(a1xq[q], 16); a1xq[q] += __shfl_xor(a1xq[q], 32);
        a1yq[q] += __shfl_xor(a1yq[q], 16); a1yq[q] += __shfl_xor(a1yq[q], 32);
        a1zq[q] += __shfl_xor(a1zq[q], 16); a1zq[q] += __shfl_xor(a1zq[q], 32);
    }
    if (lane < 16) {
        float* ar = acc + (size_t)n * 256;
        #pragma unroll
        for (int q = 0; q < 4; ++q) {
            ar[16 * q + lane]       = a0q[q];
            ar[64 + 16 * q + lane]  = a1xq[q];
            ar[128 + 16 * q + lane] = a1yq[q];
            ar[192 + 16 * q + lane] = a1zq[q];
        }
    }
}

// ---------------------------------------------------------------------------
// Node epilogue
// ---------------------------------------------------------------------------
__global__ __launch_bounds__(256) void node_out_kernel(
    const float* __restrict__ acc, const float* __restrict__ node_feats,
    const int* __restrict__ node_specie,
    const float* __restrict__ Wd0, const float* __restrict__ Wd1,
    const float* __restrict__ Ws0, const float* __restrict__ Ws1,
    float* __restrict__ out)
{
    int n = blockIdx.x;
    int t = threadIdx.x;
    __shared__ float gates[64];
    int sp = node_specie[n];
    const float* accn = acc + (size_t)n * 256;
    const float* nf = node_feats + (size_t)n * 256;

    if (t < 128) {
        const float* ws0 = Ws0 + (size_t)sp * 64 * 128;
        float f = 0.f;
        #pragma unroll 8
        for (int c = 0; c < 64; ++c) {
            f += (0.25f * accn[c]) * Wd0[c * 128 + t];
            f += nf[c] * ws0[c * 128 + t];
        }
        float sv = f / (1.f + __expf(-f));
        if (t < 64) out[(size_t)n * 256 + t] = sv;
        else        gates[t - 64] = sv;
    }
    __syncthreads();
    if (t < 192) {
        int i = t >> 6;
        int c2 = t & 63;
        const float* ws1 = Ws1 + (size_t)sp * 64 * 64;
        float f = 0.f;
        #pragma unroll 8
        for (int cc = 0; cc < 64; ++cc) {
            f += (0.25f * accn[64 + i * 64 + cc]) * Wd1[cc * 64 + c2];
            f += nf[64 + cc * 3 + i] * ws1[cc * 64 + c2];
        }
        out[(size_t)n * 256 + 64 + c2 * 3 + i] = f * gates[c2];
    }
}

// ---------------------------------------------------------------------------
extern "C" void kernel_launch(void* const* d_in, const int* in_sizes, int n_in,
                              void* d_out, int out_size, void* d_ws, size_t ws_size,
                              hipStream_t stream) {
    const float* vectors     = (const float*)d_in[0];
    const float* node_feats  = (const float*)d_in[1];
    const int*   node_specie = (const int*)d_in[2];
    const int*   senders     = (const int*)d_in[3];
    const int*   receivers   = (const int*)d_in[4];
    const float* W0_up       = (const float*)d_in[5];
    const float* W1_up       = (const float*)d_in[6];
    const float* Wm1         = (const float*)d_in[7];
    const float* Wm2         = (const float*)d_in[8];
    const float* Wm3         = (const float*)d_in[9];
    const float* Ws0         = (const float*)d_in[10];
    const float* Ws1         = (const float*)d_in[11];
    const float* Wd0         = (const float*)d_in[12];
    const float* Wd1         = (const float*)d_in[13];
    float* out = (float*)d_out;

    int E = in_sizes[0] / 3;
    int N = in_sizes[1] / 256;
    int nblk = (N + 1023) / 1024;

    char* wp = (char*)d_ws;
    float* u      = (float*)wp;                 wp += (size_t)N * 256 * 4;
    float* acc    = (float*)wp;                 wp += (size_t)N * 256 * 4;
    uint4* epackA = (uint4*)wp;                 wp += (size_t)(E + 16) * 16;
    float4* epackB = (float4*)wp;               wp += (size_t)(E + 16) * 16;
    short* W1B    = (short*)wp;                 wp += 4 * 512 * 2;
    short* Wm2B   = (short*)wp;                 wp += 8 * 512 * 2;
    short* W3B    = (short*)wp;                 wp += 40 * 512 * 2;
    int*   cnt    = (int*)wp;                   wp += (size_t)N * 4;
    int*   offs   = (int*)wp;                   wp += (size_t)(N + 1) * 4;
    int*   cursor = (int*)wp;                   wp += (size_t)N * 4;
    int*   part   = (int*)wp;                   wp += (size_t)(nblk + 1) * 4;

    hipMemsetAsync(cnt, 0, (size_t)N * sizeof(int), stream);

    prep_kernel<<<13, 256, 0, stream>>>(Wm1, Wm2, Wm3, W1B, Wm2B, W3B);
    hist_kernel<<<1024, 256, 0, stream>>>(receivers, cnt, E);
    scan1_kernel<<<nblk, 256, 0, stream>>>(cnt, offs, part, N);
    scan2_kernel<<<1, 64, 0, stream>>>(part, offs, nblk, N);
    scan3_kernel<<<nblk, 256, 0, stream>>>(offs, cursor, part, N);
    fill_pack_kernel<<<1024, 256, 0, stream>>>(
        vectors, senders, receivers, cursor, epackA, epackB, E);
    node_up_kernel<<<N, 256, 0, stream>>>(node_feats, W0_up, W1_up, u);
    edge_kernel<<<(N + 3) / 4, 256, 0, stream>>>(
        epackA, epackB, offs, (const float4*)u, W1B, Wm2B, W3B, acc, N);
    node_out_kernel<<<N, 256, 0, stream>>>(
        acc, node_feats, node_specie, Wd0, Wd1, Ws0, Ws1, out);
}

// Round 9
// 553.508 us; speedup vs baseline: 1.2921x; 1.2921x over previous
//
#include <hip/hip_runtime.h>
#include <hip/hip_bf16.h>

typedef __attribute__((ext_vector_type(8))) short short8;
typedef __attribute__((ext_vector_type(4))) float f32x4;

__device__ __forceinline__ unsigned bf16u(float x) {
    unsigned u = __float_as_uint(x);
    return (u + 0x7fffu + ((u >> 16) & 1u)) >> 16;
}
__device__ __forceinline__ short bf16s(float x) { return (short)bf16u(x); }

// ---------------------------------------------------------------------------
// Prep: pack Wm1 (8x64), Wm2 (64x64), Wm3 (64x320) into MFMA B-fragment
// layout (bf16). Frag (t,kh): lane l holds B[k=kh*32+(l>>4)*8+i][col=16t+(l&15)].
// ---------------------------------------------------------------------------
__global__ __launch_bounds__(256) void prep_kernel(
    const float* __restrict__ Wm1, const float* __restrict__ Wm2,
    const float* __restrict__ Wm3,
    short* __restrict__ W1B, short* __restrict__ Wm2B, short* __restrict__ W3B)
{
    int idx = blockIdx.x * 256 + threadIdx.x;   // 52 frags * 64 lanes
    if (idx >= 52 * 64) return;
    int l = idx & 63, f = idx >> 6;
    int g = l >> 4, c = l & 15;
    short8 v;
    if (f < 4) {                 // W1B tile t=f: k=i (g==0 only), col=16f+c
        #pragma unroll
        for (int i = 0; i < 8; ++i)
            v[i] = (g == 0) ? bf16s(Wm1[(size_t)i * 64 + f * 16 + c]) : (short)0;
        *(short8*)(W1B + (size_t)f * 512 + l * 8) = v;
    } else if (f < 12) {         // Wm2B
        int f2 = f - 4, t = f2 >> 1, kh = f2 & 1;
        #pragma unroll
        for (int i = 0; i < 8; ++i)
            v[i] = bf16s(Wm2[(size_t)(kh * 32 + g * 8 + i) * 64 + t * 16 + c]);
        *(short8*)(Wm2B + (size_t)f2 * 512 + l * 8) = v;
    } else {                     // W3B
        int f3 = f - 12, t = f3 >> 1, kh = f3 & 1;
        #pragma unroll
        for (int i = 0; i < 8; ++i)
            v[i] = bf16s(Wm3[(size_t)(kh * 32 + g * 8 + i) * 320 + t * 16 + c]);
        *(short8*)(W3B + (size_t)f3 * 512 + l * 8) = v;
    }
}

// ---------------------------------------------------------------------------
// CSR build: histogram -> 3-phase parallel scan -> bucket fill (+ pack)
// ---------------------------------------------------------------------------
__global__ __launch_bounds__(256) void hist_kernel(
    const int* __restrict__ receivers, int* __restrict__ cnt, int E)
{
    int i = blockIdx.x * 256 + threadIdx.x;
    int stride = gridDim.x * 256;
    for (; i < E; i += stride) atomicAdd(&cnt[receivers[i]], 1);
}

// scan1: each block scans 1024 elements (4/thread), writes local-exclusive
// results to offs and block total to part[b].
__global__ __launch_bounds__(256) void scan1_kernel(
    const int* __restrict__ cnt, int* __restrict__ offs,
    int* __restrict__ part, int N)
{
    __shared__ int a_[256], b_[256];
    const int b = blockIdx.x, t = threadIdx.x;
    const int base = b * 1024 + t * 4;
    int v[4];
    #pragma unroll
    for (int k = 0; k < 4; ++k) v[k] = (base + k < N) ? cnt[base + k] : 0;
    int sum = v[0] + v[1] + v[2] + v[3];
    a_[t] = sum;
    __syncthreads();
    int* src = a_; int* dst = b_;
    for (int off = 1; off < 256; off <<= 1) {
        dst[t] = src[t] + ((t >= off) ? src[t - off] : 0);
        __syncthreads();
        int* tmp = src; src = dst; dst = tmp;
    }
    int excl = src[t] - sum;
    if (t == 0) part[b] = src[255];
    int run = excl;
    #pragma unroll
    for (int k = 0; k < 4; ++k) {
        if (base + k < N) offs[base + k] = run;
        run += v[k];
    }
}

// scan2: serial exclusive scan of block partials (nblk small), total -> offs[N]
__global__ void scan2_kernel(int* __restrict__ part, int* __restrict__ offs,
                             int nblk, int N)
{
    if (threadIdx.x == 0 && blockIdx.x == 0) {
        int running = 0;
        for (int i = 0; i < nblk; ++i) {
            int tmp = part[i];
            part[i] = running;
            running += tmp;
        }
        offs[N] = running;
    }
}

// scan3: add block base to offs, mirror into cursor
__global__ __launch_bounds__(256) void scan3_kernel(
    int* __restrict__ offs, int* __restrict__ cursor,
    const int* __restrict__ part, int N)
{
    const int b = blockIdx.x, t = threadIdx.x;
    const int add = part[b];
    const int base = b * 1024 + t * 4;
    #pragma unroll
    for (int k = 0; k < 4; ++k) {
        int i = base + k;
        if (i < N) {
            int o = offs[i] + add;
            offs[i] = o;
            cursor[i] = o;
        }
    }
}

// Scatter per-edge packed record into CSR position:
//  epackA[pos] = basis[0..7] bf16 pairs (MFMA A-fragment data)
//  epackB[pos] = { Yx, Yy, Yz, sender_bits }
__global__ __launch_bounds__(256) void fill_pack_kernel(
    const float* __restrict__ vectors, const int* __restrict__ senders,
    const int* __restrict__ receivers, int* __restrict__ cursor,
    uint4* __restrict__ epackA, float4* __restrict__ epackB, int E)
{
    int i = blockIdx.x * 256 + threadIdx.x;
    int stride = gridDim.x * 256;
    for (; i < E; i += stride) {
        int pos = atomicAdd(&cursor[receivers[i]], 1);
        float vx = vectors[3 * (size_t)i + 0];
        float vy = vectors[3 * (size_t)i + 1];
        float vz = vectors[3 * (size_t)i + 2];
        float r = sqrtf(vx * vx + vy * vy + vz * vz);
        float ir = (r != 0.f) ? 1.f / r : 0.f;
        float ang = r * 0.6283185307179586f;   // pi/5
        float s1, c1;
        __sincosf(ang, &s1, &c1);
        float tc = 2.f * c1;
        float sb = s1, sp = 0.f;
        float coef = 0.6324555320336759f * ir;
        unsigned bw[4];
        #pragma unroll
        for (int h = 0; h < 4; ++h) {
            unsigned lo = bf16u(sb * coef);
            float nx = tc * sb - sp; sp = sb; sb = nx;
            unsigned hi = bf16u(sb * coef);
            nx = tc * sb - sp; sp = sb; sb = nx;
            bw[h] = lo | (hi << 16);
        }
        epackA[pos] = make_uint4(bw[0], bw[1], bw[2], bw[3]);
        epackB[pos] = make_float4(vx * ir, vy * ir, vz * ir,
                                  __int_as_float(senders[i]));
    }
}

// ---------------------------------------------------------------------------
// Node up-projection, d-major interleaved output:
// u[n*256 + d*4 + comp], comp 0..3 = {u0, u1x, u1y, u1z}[d]
// -> per-(edge,q) gather in edge_kernel is one float4 per lane.
// ---------------------------------------------------------------------------
__global__ __launch_bounds__(256) void node_up_kernel(
    const float* __restrict__ node_feats, const float* __restrict__ W0_up,
    const float* __restrict__ W1_up, float* __restrict__ u)
{
    int n = blockIdx.x;
    int t = threadIdx.x;
    const float* nf = node_feats + (size_t)n * 256;
    int comp = t >> 6, d = t & 63;
    float f = 0.f;
    if (comp == 0) {
        #pragma unroll 8
        for (int c = 0; c < 64; ++c) f += nf[c] * W0_up[c * 64 + d];
    } else {
        int i = comp - 1;
        #pragma unroll 8
        for (int c = 0; c < 64; ++c) f += nf[64 + c * 3 + i] * W1_up[c * 64 + d];
    }
    u[(size_t)n * 256 + d * 4 + comp] = f;
}

// ---------------------------------------------------------------------------
// Edge kernel v8: wave per receiver node, 16-edge MFMA chunks.
//  - __launch_bounds__(256,2): give the allocator 256 VGPRs -> NO SPILL
//    (R5-R7 all spilled ~1.6GB of scratch traffic under the (256,3) cap)
//  - u gathered as d-major float4: one dwordx4/lane
//  - W3B fragments staged in LDS; ping-pong pipelined q loop
// ---------------------------------------------------------------------------
__global__ __launch_bounds__(256, 2) void edge_kernel(
    const uint4* __restrict__ epackA, const float4* __restrict__ epackB,
    const int* __restrict__ offs, const float4* __restrict__ u4,
    const short* __restrict__ W1B, const short* __restrict__ Wm2B,
    const short* __restrict__ W3B, float* __restrict__ acc, int N)
{
    __shared__ __align__(16) short ldsW3[40 * 512];   // 40KB staged W3B
    __shared__ __align__(16) short ldsH[4][1024];     // per-wave h buffer (swz)
    __shared__ __align__(16) float ldsMeta[4][16][4]; // Y.xyz + sender

    {   // cooperative stage of W3B (2560 short8)
        const short8* src = (const short8*)W3B;
        short8* dst = (short8*)ldsW3;
        for (int i = threadIdx.x; i < 2560; i += 256) dst[i] = src[i];
    }
    __syncthreads();

    const int lane = threadIdx.x & 63;
    const int wv   = threadIdx.x >> 6;
    const int n    = blockIdx.x * 4 + wv;
    if (n >= N) return;
    const int c = lane & 15, g = lane >> 4;

    float a0q[4]  = {0.f, 0.f, 0.f, 0.f};
    float a1xq[4] = {0.f, 0.f, 0.f, 0.f};
    float a1yq[4] = {0.f, 0.f, 0.f, 0.f};
    float a1zq[4] = {0.f, 0.f, 0.f, 0.f};

    const int beg = offs[n], end = offs[n + 1];

    for (int p0 = beg; p0 < end; p0 += 16) {
        const int m = end - p0;

        // ---- prologue: lanes 0-15, one packed record each ----
        short8 basisA = {0, 0, 0, 0, 0, 0, 0, 0};
        if (lane < 16) {
            uint4 ba = epackA[p0 + lane];
            float4 mb = epackB[p0 + lane];
            if (lane >= m) {
                ba = make_uint4(0u, 0u, 0u, 0u);
                mb = make_float4(0.f, 0.f, 0.f, __int_as_float(0));
            }
            union { uint4 u4v; short8 s8; } cv;
            cv.u4v = ba;
            basisA = cv.s8;
            *(float4*)&ldsMeta[wv][lane][0] = mb;
        }

        // ---- per-lane edge meta for its 4 rows ----
        float Yx[4], Yy[4], Yz[4];
        int snd[4];
        #pragma unroll
        for (int i = 0; i < 4; ++i) {
            int row = 4 * g + i;
            float4 mt = *(const float4*)&ldsMeta[wv][row][0];
            Yx[i] = mt.x; Yy[i] = mt.y; Yz[i] = mt.z;
            snd[i] = __float_as_int(mt.w);
        }

#define PFETCH(Q, M0, M1X, M1Y, M1Z)                                        \
        _Pragma("unroll")                                                   \
        for (int i = 0; i < 4; ++i) {                                       \
            float4 mv = u4[(size_t)snd[i] * 64 + 16 * (Q) + c];             \
            M0[i]  = mv.x; M1X[i] = mv.y;                                   \
            M1Y[i] = mv.z; M1Z[i] = mv.w;                                   \
        }

#define COMPQ(Q, M0, M1X, M1Y, M1Z)                                         \
        _Pragma("unroll")                                                   \
        for (int p = 0; p < 5; ++p) {                                       \
            const int t = 4 * p + (Q);                                      \
            f32x4 w = {0.f, 0.f, 0.f, 0.f};                                 \
            short8 b0 = *(const short8*)(ldsW3 + (size_t)(t * 2) * 512 + lane * 8);     \
            short8 b1 = *(const short8*)(ldsW3 + (size_t)(t * 2 + 1) * 512 + lane * 8); \
            w = __builtin_amdgcn_mfma_f32_16x16x32_bf16(h2f0, b0, w, 0, 0, 0);          \
            w = __builtin_amdgcn_mfma_f32_16x16x32_bf16(h2f1, b1, w, 0, 0, 0);          \
            _Pragma("unroll")                                               \
            for (int i = 0; i < 4; ++i) {                                   \
                float wv_ = w[i];                                           \
                if (p == 0) {                                               \
                    a0q[Q] += wv_ * M0[i];                                  \
                } else if (p == 1) {                                        \
                    float tt = wv_ * M0[i];                                 \
                    a1xq[Q] += tt * Yx[i];                                  \
                    a1yq[Q] += tt * Yy[i];                                  \
                    a1zq[Q] += tt * Yz[i];                                  \
                } else if (p == 2) {                                        \
                    a1xq[Q] += wv_ * M1X[i];                                \
                    a1yq[Q] += wv_ * M1Y[i];                                \
                    a1zq[Q] += wv_ * M1Z[i];                                \
                } else if (p == 3) {                                        \
                    a0q[Q] += wv_ * (M1X[i] * Yx[i] + M1Y[i] * Yy[i] + M1Z[i] * Yz[i]); \
                } else {                                                    \
                    a1xq[Q] += wv_ * (M1Y[i] * Yz[i] - M1Z[i] * Yy[i]);     \
                    a1yq[Q] += wv_ * (M1Z[i] * Yx[i] - M1X[i] * Yz[i]);     \
                    a1zq[Q] += wv_ * (M1X[i] * Yy[i] - M1Y[i] * Yx[i]);     \
                }                                                           \
            }                                                               \
        }

        float m0A[4], m1xA[4], m1yA[4], m1zA[4];
        float m0B[4], m1xB[4], m1yB[4], m1zB[4];
        PFETCH(0, m0A, m1xA, m1yA, m1zA);
        PFETCH(1, m0B, m1xB, m1yB, m1zB);
        __builtin_amdgcn_sched_barrier(0);   // keep gathers issued here

        // ---- layer 1: 4 MFMAs; silu -> ldsH (swizzled bf16) ----
        #pragma unroll
        for (int t = 0; t < 4; ++t) {
            f32x4 h = {0.f, 0.f, 0.f, 0.f};
            short8 bf = *(const short8*)(W1B + (size_t)t * 512 + lane * 8);
            h = __builtin_amdgcn_mfma_f32_16x16x32_bf16(basisA, bf, h, 0, 0, 0);
            #pragma unroll
            for (int i = 0; i < 4; ++i) {
                float x = h[i];
                float h1 = x / (1.f + __expf(-x));
                int row = 4 * g + i;
                ldsH[wv][row * 64 + ((16 * t + c) ^ ((row & 7) << 3))] = bf16s(h1);
            }
        }
        short8 h1f0 = *(const short8*)&ldsH[wv][c * 64 + ((g * 8) ^ ((c & 7) << 3))];
        short8 h1f1 = *(const short8*)&ldsH[wv][c * 64 + ((32 + g * 8) ^ ((c & 7) << 3))];

        // ---- layer 2: 8 MFMAs; silu -> ldsH (reuse) ----
        #pragma unroll
        for (int t = 0; t < 4; ++t) {
            f32x4 h = {0.f, 0.f, 0.f, 0.f};
            short8 b0 = *(const short8*)(Wm2B + (size_t)(t * 2) * 512 + lane * 8);
            short8 b1 = *(const short8*)(Wm2B + (size_t)(t * 2 + 1) * 512 + lane * 8);
            h = __builtin_amdgcn_mfma_f32_16x16x32_bf16(h1f0, b0, h, 0, 0, 0);
            h = __builtin_amdgcn_mfma_f32_16x16x32_bf16(h1f1, b1, h, 0, 0, 0);
            #pragma unroll
            for (int i = 0; i < 4; ++i) {
                float x = h[i];
                float h2 = x / (1.f + __expf(-x));
                int row = 4 * g + i;
                ldsH[wv][row * 64 + ((16 * t + c) ^ ((row & 7) << 3))] = bf16s(h2);
            }
        }
        short8 h2f0 = *(const short8*)&ldsH[wv][c * 64 + ((g * 8) ^ ((c & 7) << 3))];
        short8 h2f1 = *(const short8*)&ldsH[wv][c * 64 + ((32 + g * 8) ^ ((c & 7) << 3))];

        // ---- layer 3 + fused messages, ping-pong pipelined over q ----
        COMPQ(0, m0A, m1xA, m1yA, m1zA);
        __builtin_amdgcn_sched_barrier(0);
        PFETCH(2, m0A, m1xA, m1yA, m1zA);
        COMPQ(1, m0B, m1xB, m1yB, m1zB);
        __builtin_amdgcn_sched_barrier(0);
        PFETCH(3, m0B, m1xB, m1yB, m1zB);
        COMPQ(2, m0A, m1xA, m1yA, m1zA);
        __builtin_amdgcn_sched_barrier(0);
        COMPQ(3, m0B, m1xB, m1yB, m1zB);
#undef PFETCH
#undef COMPQ
    }

    // ---- reduce across the 4 g-groups and store ----
    #pragma unroll
    for (int q = 0; q < 4; ++q) {
        a0q[q]  += __shfl_xor(a0q[q], 16);  a0q[q]  += __shfl_xor(a0q[q], 32);
        a1xq[q] += __shfl_xor(a1xq[q], 16); a1xq[q] += __shfl_xor(a1xq[q], 32);
        a1yq[q] += __shfl_xor(a1yq[q], 16); a1yq[q] += __shfl_xor(a1yq[q], 32);
        a1zq[q] += __shfl_xor(a1zq[q], 16); a1zq[q] += __shfl_xor(a1zq[q], 32);
    }
    if (lane < 16) {
        float* ar = acc + (size_t)n * 256;
        #pragma unroll
        for (int q = 0; q < 4; ++q) {
            ar[16 * q + lane]       = a0q[q];
            ar[64 + 16 * q + lane]  = a1xq[q];
            ar[128 + 16 * q + lane] = a1yq[q];
            ar[192 + 16 * q + lane] = a1zq[q];
        }
    }
}

// ---------------------------------------------------------------------------
// Node epilogue
// ---------------------------------------------------------------------------
__global__ __launch_bounds__(256) void node_out_kernel(
    const float* __restrict__ acc, const float* __restrict__ node_feats,
    const int* __restrict__ node_specie,
    const float* __restrict__ Wd0, const float* __restrict__ Wd1,
    const float* __restrict__ Ws0, const float* __restrict__ Ws1,
    float* __restrict__ out)
{
    int n = blockIdx.x;
    int t = threadIdx.x;
    __shared__ float gates[64];
    int sp = node_specie[n];
    const float* accn = acc + (size_t)n * 256;
    const float* nf = node_feats + (size_t)n * 256;

    if (t < 128) {
        const float* ws0 = Ws0 + (size_t)sp * 64 * 128;
        float f = 0.f;
        #pragma unroll 8
        for (int c = 0; c < 64; ++c) {
            f += (0.25f * accn[c]) * Wd0[c * 128 + t];
            f += nf[c] * ws0[c * 128 + t];
        }
        float sv = f / (1.f + __expf(-f));
        if (t < 64) out[(size_t)n * 256 + t] = sv;
        else        gates[t - 64] = sv;
    }
    __syncthreads();
    if (t < 192) {
        int i = t >> 6;
        int c2 = t & 63;
        const float* ws1 = Ws1 + (size_t)sp * 64 * 64;
        float f = 0.f;
        #pragma unroll 8
        for (int cc = 0; cc < 64; ++cc) {
            f += (0.25f * accn[64 + i * 64 + cc]) * Wd1[cc * 64 + c2];
            f += nf[64 + cc * 3 + i] * ws1[cc * 64 + c2];
        }
        out[(size_t)n * 256 + 64 + c2 * 3 + i] = f * gates[c2];
    }
}

// ---------------------------------------------------------------------------
extern "C" void kernel_launch(void* const* d_in, const int* in_sizes, int n_in,
                              void* d_out, int out_size, void* d_ws, size_t ws_size,
                              hipStream_t stream) {
    const float* vectors     = (const float*)d_in[0];
    const float* node_feats  = (const float*)d_in[1];
    const int*   node_specie = (const int*)d_in[2];
    const int*   senders     = (const int*)d_in[3];
    const int*   receivers   = (const int*)d_in[4];
    const float* W0_up       = (const float*)d_in[5];
    const float* W1_up       = (const float*)d_in[6];
    const float* Wm1         = (const float*)d_in[7];
    const float* Wm2         = (const float*)d_in[8];
    const float* Wm3         = (const float*)d_in[9];
    const float* Ws0         = (const float*)d_in[10];
    const float* Ws1         = (const float*)d_in[11];
    const float* Wd0         = (const float*)d_in[12];
    const float* Wd1         = (const float*)d_in[13];
    float* out = (float*)d_out;

    int E = in_sizes[0] / 3;
    int N = in_sizes[1] / 256;
    int nblk = (N + 1023) / 1024;

    char* wp = (char*)d_ws;
    float* u      = (float*)wp;                 wp += (size_t)N * 256 * 4;
    float* acc    = (float*)wp;                 wp += (size_t)N * 256 * 4;
    uint4* epackA = (uint4*)wp;                 wp += (size_t)(E + 16) * 16;
    float4* epackB = (float4*)wp;               wp += (size_t)(E + 16) * 16;
    short* W1B    = (short*)wp;                 wp += 4 * 512 * 2;
    short* Wm2B   = (short*)wp;                 wp += 8 * 512 * 2;
    short* W3B    = (short*)wp;                 wp += 40 * 512 * 2;
    int*   cnt    = (int*)wp;                   wp += (size_t)N * 4;
    int*   offs   = (int*)wp;                   wp += (size_t)(N + 1) * 4;
    int*   cursor = (int*)wp;                   wp += (size_t)N * 4;
    int*   part   = (int*)wp;                   wp += (size_t)(nblk + 1) * 4;

    hipMemsetAsync(cnt, 0, (size_t)N * sizeof(int), stream);

    prep_kernel<<<13, 256, 0, stream>>>(Wm1, Wm2, Wm3, W1B, Wm2B, W3B);
    hist_kernel<<<1024, 256, 0, stream>>>(receivers, cnt, E);
    scan1_kernel<<<nblk, 256, 0, stream>>>(cnt, offs, part, N);
    scan2_kernel<<<1, 64, 0, stream>>>(part, offs, nblk, N);
    scan3_kernel<<<nblk, 256, 0, stream>>>(offs, cursor, part, N);
    fill_pack_kernel<<<1024, 256, 0, stream>>>(
        vectors, senders, receivers, cursor, epackA, epackB, E);
    node_up_kernel<<<N, 256, 0, stream>>>(node_feats, W0_up, W1_up, u);
    edge_kernel<<<(N + 3) / 4, 256, 0, stream>>>(
        epackA, epackB, offs, (const float4*)u, W1B, Wm2B, W3B, acc, N);
    node_out_kernel<<<N, 256, 0, stream>>>(
        acc, node_feats, node_specie, Wd0, Wd1, Ws0, Ws1, out);
}

// Round 10
// 500.572 us; speedup vs baseline: 1.4287x; 1.1058x over previous
//
#include <hip/hip_runtime.h>
#include <hip/hip_bf16.h>

typedef __attribute__((ext_vector_type(8))) short short8;
typedef __attribute__((ext_vector_type(4))) float f32x4;

__device__ __forceinline__ unsigned bf16u(float x) {
    unsigned u = __float_as_uint(x);
    return (u + 0x7fffu + ((u >> 16) & 1u)) >> 16;
}
__device__ __forceinline__ short bf16s(float x) { return (short)bf16u(x); }

// ---------------------------------------------------------------------------
// Prep: pack Wm1 (8x64), Wm2 (64x64), Wm3 (64x320) into MFMA B-fragment
// layout (bf16). Frag (t,kh): lane l holds B[k=kh*32+(l>>4)*8+i][col=16t+(l&15)].
// ---------------------------------------------------------------------------
__global__ __launch_bounds__(256) void prep_kernel(
    const float* __restrict__ Wm1, const float* __restrict__ Wm2,
    const float* __restrict__ Wm3,
    short* __restrict__ W1B, short* __restrict__ Wm2B, short* __restrict__ W3B)
{
    int idx = blockIdx.x * 256 + threadIdx.x;   // 52 frags * 64 lanes
    if (idx >= 52 * 64) return;
    int l = idx & 63, f = idx >> 6;
    int g = l >> 4, c = l & 15;
    short8 v;
    if (f < 4) {                 // W1B tile t=f: k=i (g==0 only), col=16f+c
        #pragma unroll
        for (int i = 0; i < 8; ++i)
            v[i] = (g == 0) ? bf16s(Wm1[(size_t)i * 64 + f * 16 + c]) : (short)0;
        *(short8*)(W1B + (size_t)f * 512 + l * 8) = v;
    } else if (f < 12) {         // Wm2B
        int f2 = f - 4, t = f2 >> 1, kh = f2 & 1;
        #pragma unroll
        for (int i = 0; i < 8; ++i)
            v[i] = bf16s(Wm2[(size_t)(kh * 32 + g * 8 + i) * 64 + t * 16 + c]);
        *(short8*)(Wm2B + (size_t)f2 * 512 + l * 8) = v;
    } else {                     // W3B
        int f3 = f - 12, t = f3 >> 1, kh = f3 & 1;
        #pragma unroll
        for (int i = 0; i < 8; ++i)
            v[i] = bf16s(Wm3[(size_t)(kh * 32 + g * 8 + i) * 320 + t * 16 + c]);
        *(short8*)(W3B + (size_t)f3 * 512 + l * 8) = v;
    }
}

// ---------------------------------------------------------------------------
// CSR build: histogram -> 3-phase parallel scan -> bucket fill (+ pack)
// ---------------------------------------------------------------------------
__global__ __launch_bounds__(256) void hist_kernel(
    const int* __restrict__ receivers, int* __restrict__ cnt, int E)
{
    int i = blockIdx.x * 256 + threadIdx.x;
    int stride = gridDim.x * 256;
    for (; i < E; i += stride) atomicAdd(&cnt[receivers[i]], 1);
}

// scan1: each block scans 1024 elements (4/thread), writes local-exclusive
// results to offs and block total to part[b].
__global__ __launch_bounds__(256) void scan1_kernel(
    const int* __restrict__ cnt, int* __restrict__ offs,
    int* __restrict__ part, int N)
{
    __shared__ int a_[256], b_[256];
    const int b = blockIdx.x, t = threadIdx.x;
    const int base = b * 1024 + t * 4;
    int v[4];
    #pragma unroll
    for (int k = 0; k < 4; ++k) v[k] = (base + k < N) ? cnt[base + k] : 0;
    int sum = v[0] + v[1] + v[2] + v[3];
    a_[t] = sum;
    __syncthreads();
    int* src = a_; int* dst = b_;
    for (int off = 1; off < 256; off <<= 1) {
        dst[t] = src[t] + ((t >= off) ? src[t - off] : 0);
        __syncthreads();
        int* tmp = src; src = dst; dst = tmp;
    }
    int excl = src[t] - sum;
    if (t == 0) part[b] = src[255];
    int run = excl;
    #pragma unroll
    for (int k = 0; k < 4; ++k) {
        if (base + k < N) offs[base + k] = run;
        run += v[k];
    }
}

// scan2: serial exclusive scan of block partials (nblk small), total -> offs[N]
__global__ void scan2_kernel(int* __restrict__ part, int* __restrict__ offs,
                             int nblk, int N)
{
    if (threadIdx.x == 0 && blockIdx.x == 0) {
        int running = 0;
        for (int i = 0; i < nblk; ++i) {
            int tmp = part[i];
            part[i] = running;
            running += tmp;
        }
        offs[N] = running;
    }
}

// scan3: add block base to offs, mirror into cursor
__global__ __launch_bounds__(256) void scan3_kernel(
    int* __restrict__ offs, int* __restrict__ cursor,
    const int* __restrict__ part, int N)
{
    const int b = blockIdx.x, t = threadIdx.x;
    const int add = part[b];
    const int base = b * 1024 + t * 4;
    #pragma unroll
    for (int k = 0; k < 4; ++k) {
        int i = base + k;
        if (i < N) {
            int o = offs[i] + add;
            offs[i] = o;
            cursor[i] = o;
        }
    }
}

// Scatter per-edge packed record into CSR position:
//  epackA[pos] = basis[0..7] bf16 pairs (MFMA A-fragment data)
//  epackB[pos] = { Yx, Yy, Yz, sender_bits }
__global__ __launch_bounds__(256) void fill_pack_kernel(
    const float* __restrict__ vectors, const int* __restrict__ senders,
    const int* __restrict__ receivers, int* __restrict__ cursor,
    uint4* __restrict__ epackA, float4* __restrict__ epackB, int E)
{
    int i = blockIdx.x * 256 + threadIdx.x;
    int stride = gridDim.x * 256;
    for (; i < E; i += stride) {
        int pos = atomicAdd(&cursor[receivers[i]], 1);
        float vx = vectors[3 * (size_t)i + 0];
        float vy = vectors[3 * (size_t)i + 1];
        float vz = vectors[3 * (size_t)i + 2];
        float r = sqrtf(vx * vx + vy * vy + vz * vz);
        float ir = (r != 0.f) ? 1.f / r : 0.f;
        float ang = r * 0.6283185307179586f;   // pi/5
        float s1, c1;
        __sincosf(ang, &s1, &c1);
        float tc = 2.f * c1;
        float sb = s1, sp = 0.f;
        float coef = 0.6324555320336759f * ir;
        unsigned bw[4];
        #pragma unroll
        for (int h = 0; h < 4; ++h) {
            unsigned lo = bf16u(sb * coef);
            float nx = tc * sb - sp; sp = sb; sb = nx;
            unsigned hi = bf16u(sb * coef);
            nx = tc * sb - sp; sp = sb; sb = nx;
            bw[h] = lo | (hi << 16);
        }
        epackA[pos] = make_uint4(bw[0], bw[1], bw[2], bw[3]);
        epackB[pos] = make_float4(vx * ir, vy * ir, vz * ir,
                                  __int_as_float(senders[i]));
    }
}

// ---------------------------------------------------------------------------
// Node up-projection, d-major interleaved output:
// u[n*256 + d*4 + comp], comp 0..3 = {u0, u1x, u1y, u1z}[d]
// -> per-(edge,q) gather in edge_kernel is one float4 per lane.
// ---------------------------------------------------------------------------
__global__ __launch_bounds__(256) void node_up_kernel(
    const float* __restrict__ node_feats, const float* __restrict__ W0_up,
    const float* __restrict__ W1_up, float* __restrict__ u)
{
    int n = blockIdx.x;
    int t = threadIdx.x;
    const float* nf = node_feats + (size_t)n * 256;
    int comp = t >> 6, d = t & 63;
    float f = 0.f;
    if (comp == 0) {
        #pragma unroll 8
        for (int c = 0; c < 64; ++c) f += nf[c] * W0_up[c * 64 + d];
    } else {
        int i = comp - 1;
        #pragma unroll 8
        for (int c = 0; c < 64; ++c) f += nf[64 + c * 3 + i] * W1_up[c * 64 + d];
    }
    u[(size_t)n * 256 + d * 4 + comp] = f;
}

// ---------------------------------------------------------------------------
// Edge kernel v9: wave per receiver node, 16-edge MFMA chunks.
//  - PLAIN __launch_bounds__(256): R4/R9 A/B showed any min-waves hint makes
//    the allocator snap to 128 regs and spill ~900MB/dispatch of scratch.
//    Live set ~150-240 regs gives the SAME 2 waves/SIMD occupancy spill-free.
//  - u gathered as d-major float4: one dwordx4/lane
//  - W3B fragments staged in LDS; ping-pong pipelined q loop
// ---------------------------------------------------------------------------
__global__ __launch_bounds__(256) void edge_kernel(
    const uint4* __restrict__ epackA, const float4* __restrict__ epackB,
    const int* __restrict__ offs, const float4* __restrict__ u4,
    const short* __restrict__ W1B, const short* __restrict__ Wm2B,
    const short* __restrict__ W3B, float* __restrict__ acc, int N)
{
    __shared__ __align__(16) short ldsW3[40 * 512];   // 40KB staged W3B
    __shared__ __align__(16) short ldsH[4][1024];     // per-wave h buffer (swz)
    __shared__ __align__(16) float ldsMeta[4][16][4]; // Y.xyz + sender

    {   // cooperative stage of W3B (2560 short8)
        const short8* src = (const short8*)W3B;
        short8* dst = (short8*)ldsW3;
        for (int i = threadIdx.x; i < 2560; i += 256) dst[i] = src[i];
    }
    __syncthreads();

    const int lane = threadIdx.x & 63;
    const int wv   = threadIdx.x >> 6;
    const int n    = blockIdx.x * 4 + wv;
    if (n >= N) return;
    const int c = lane & 15, g = lane >> 4;

    float a0q[4]  = {0.f, 0.f, 0.f, 0.f};
    float a1xq[4] = {0.f, 0.f, 0.f, 0.f};
    float a1yq[4] = {0.f, 0.f, 0.f, 0.f};
    float a1zq[4] = {0.f, 0.f, 0.f, 0.f};

    const int beg = offs[n], end = offs[n + 1];

    for (int p0 = beg; p0 < end; p0 += 16) {
        const int m = end - p0;

        // ---- prologue: lanes 0-15, one packed record each ----
        short8 basisA = {0, 0, 0, 0, 0, 0, 0, 0};
        if (lane < 16) {
            uint4 ba = epackA[p0 + lane];
            float4 mb = epackB[p0 + lane];
            if (lane >= m) {
                ba = make_uint4(0u, 0u, 0u, 0u);
                mb = make_float4(0.f, 0.f, 0.f, __int_as_float(0));
            }
            union { uint4 u4v; short8 s8; } cv;
            cv.u4v = ba;
            basisA = cv.s8;
            *(float4*)&ldsMeta[wv][lane][0] = mb;
        }

        // ---- per-lane edge meta for its 4 rows ----
        float Yx[4], Yy[4], Yz[4];
        int snd[4];
        #pragma unroll
        for (int i = 0; i < 4; ++i) {
            int row = 4 * g + i;
            float4 mt = *(const float4*)&ldsMeta[wv][row][0];
            Yx[i] = mt.x; Yy[i] = mt.y; Yz[i] = mt.z;
            snd[i] = __float_as_int(mt.w);
        }

#define PFETCH(Q, M0, M1X, M1Y, M1Z)                                        \
        _Pragma("unroll")                                                   \
        for (int i = 0; i < 4; ++i) {                                       \
            float4 mv = u4[(size_t)snd[i] * 64 + 16 * (Q) + c];             \
            M0[i]  = mv.x; M1X[i] = mv.y;                                   \
            M1Y[i] = mv.z; M1Z[i] = mv.w;                                   \
        }

#define COMPQ(Q, M0, M1X, M1Y, M1Z)                                         \
        _Pragma("unroll")                                                   \
        for (int p = 0; p < 5; ++p) {                                       \
            const int t = 4 * p + (Q);                                      \
            f32x4 w = {0.f, 0.f, 0.f, 0.f};                                 \
            short8 b0 = *(const short8*)(ldsW3 + (size_t)(t * 2) * 512 + lane * 8);     \
            short8 b1 = *(const short8*)(ldsW3 + (size_t)(t * 2 + 1) * 512 + lane * 8); \
            w = __builtin_amdgcn_mfma_f32_16x16x32_bf16(h2f0, b0, w, 0, 0, 0);          \
            w = __builtin_amdgcn_mfma_f32_16x16x32_bf16(h2f1, b1, w, 0, 0, 0);          \
            _Pragma("unroll")                                               \
            for (int i = 0; i < 4; ++i) {                                   \
                float wv_ = w[i];                                           \
                if (p == 0) {                                               \
                    a0q[Q] += wv_ * M0[i];                                  \
                } else if (p == 1) {                                        \
                    float tt = wv_ * M0[i];                                 \
                    a1xq[Q] += tt * Yx[i];                                  \
                    a1yq[Q] += tt * Yy[i];                                  \
                    a1zq[Q] += tt * Yz[i];                                  \
                } else if (p == 2) {                                        \
                    a1xq[Q] += wv_ * M1X[i];                                \
                    a1yq[Q] += wv_ * M1Y[i];                                \
                    a1zq[Q] += wv_ * M1Z[i];                                \
                } else if (p == 3) {                                        \
                    a0q[Q] += wv_ * (M1X[i] * Yx[i] + M1Y[i] * Yy[i] + M1Z[i] * Yz[i]); \
                } else {                                                    \
                    a1xq[Q] += wv_ * (M1Y[i] * Yz[i] - M1Z[i] * Yy[i]);     \
                    a1yq[Q] += wv_ * (M1Z[i] * Yx[i] - M1X[i] * Yz[i]);     \
                    a1zq[Q] += wv_ * (M1X[i] * Yy[i] - M1Y[i] * Yx[i]);     \
                }                                                           \
            }                                                               \
        }

        float m0A[4], m1xA[4], m1yA[4], m1zA[4];
        float m0B[4], m1xB[4], m1yB[4], m1zB[4];
        PFETCH(0, m0A, m1xA, m1yA, m1zA);
        PFETCH(1, m0B, m1xB, m1yB, m1zB);
        __builtin_amdgcn_sched_barrier(0);   // keep gathers issued here

        // ---- layer 1: 4 MFMAs; silu -> ldsH (swizzled bf16) ----
        #pragma unroll
        for (int t = 0; t < 4; ++t) {
            f32x4 h = {0.f, 0.f, 0.f, 0.f};
            short8 bf = *(const short8*)(W1B + (size_t)t * 512 + lane * 8);
            h = __builtin_amdgcn_mfma_f32_16x16x32_bf16(basisA, bf, h, 0, 0, 0);
            #pragma unroll
            for (int i = 0; i < 4; ++i) {
                float x = h[i];
                float h1 = x / (1.f + __expf(-x));
                int row = 4 * g + i;
                ldsH[wv][row * 64 + ((16 * t + c) ^ ((row & 7) << 3))] = bf16s(h1);
            }
        }
        short8 h1f0 = *(const short8*)&ldsH[wv][c * 64 + ((g * 8) ^ ((c & 7) << 3))];
        short8 h1f1 = *(const short8*)&ldsH[wv][c * 64 + ((32 + g * 8) ^ ((c & 7) << 3))];

        // ---- layer 2: 8 MFMAs; silu -> ldsH (reuse) ----
        #pragma unroll
        for (int t = 0; t < 4; ++t) {
            f32x4 h = {0.f, 0.f, 0.f, 0.f};
            short8 b0 = *(const short8*)(Wm2B + (size_t)(t * 2) * 512 + lane * 8);
            short8 b1 = *(const short8*)(Wm2B + (size_t)(t * 2 + 1) * 512 + lane * 8);
            h = __builtin_amdgcn_mfma_f32_16x16x32_bf16(h1f0, b0, h, 0, 0, 0);
            h = __builtin_amdgcn_mfma_f32_16x16x32_bf16(h1f1, b1, h, 0, 0, 0);
            #pragma unroll
            for (int i = 0; i < 4; ++i) {
                float x = h[i];
                float h2 = x / (1.f + __expf(-x));
                int row = 4 * g + i;
                ldsH[wv][row * 64 + ((16 * t + c) ^ ((row & 7) << 3))] = bf16s(h2);
            }
        }
        short8 h2f0 = *(const short8*)&ldsH[wv][c * 64 + ((g * 8) ^ ((c & 7) << 3))];
        short8 h2f1 = *(const short8*)&ldsH[wv][c * 64 + ((32 + g * 8) ^ ((c & 7) << 3))];

        // ---- layer 3 + fused messages, ping-pong pipelined over q ----
        COMPQ(0, m0A, m1xA, m1yA, m1zA);
        __builtin_amdgcn_sched_barrier(0);
        PFETCH(2, m0A, m1xA, m1yA, m1zA);
        COMPQ(1, m0B, m1xB, m1yB, m1zB);
        __builtin_amdgcn_sched_barrier(0);
        PFETCH(3, m0B, m1xB, m1yB, m1zB);
        COMPQ(2, m0A, m1xA, m1yA, m1zA);
        __builtin_amdgcn_sched_barrier(0);
        COMPQ(3, m0B, m1xB, m1yB, m1zB);
#undef PFETCH
#undef COMPQ
    }

    // ---- reduce across the 4 g-groups and store ----
    #pragma unroll
    for (int q = 0; q < 4; ++q) {
        a0q[q]  += __shfl_xor(a0q[q], 16);  a0q[q]  += __shfl_xor(a0q[q], 32);
        a1xq[q] += __shfl_xor(a1xq[q], 16); a1xq[q] += __shfl_xor(a1xq[q], 32);
        a1yq[q] += __shfl_xor(a1yq[q], 16); a1yq[q] += __shfl_xor(a1yq[q], 32);
        a1zq[q] += __shfl_xor(a1zq[q], 16); a1zq[q] += __shfl_xor(a1zq[q], 32);
    }
    if (lane < 16) {
        float* ar = acc + (size_t)n * 256;
        #pragma unroll
        for (int q = 0; q < 4; ++q) {
            ar[16 * q + lane]       = a0q[q];
            ar[64 + 16 * q + lane]  = a1xq[q];
            ar[128 + 16 * q + lane] = a1yq[q];
            ar[192 + 16 * q + lane] = a1zq[q];
        }
    }
}

// ---------------------------------------------------------------------------
// Node epilogue
// ---------------------------------------------------------------------------
__global__ __launch_bounds__(256) void node_out_kernel(
    const float* __restrict__ acc, const float* __restrict__ node_feats,
    const int* __restrict__ node_specie,
    const float* __restrict__ Wd0, const float* __restrict__ Wd1,
    const float* __restrict__ Ws0, const float* __restrict__ Ws1,
    float* __restrict__ out)
{
    int n = blockIdx.x;
    int t = threadIdx.x;
    __shared__ float gates[64];
    int sp = node_specie[n];
    const float* accn = acc + (size_t)n * 256;
    const float* nf = node_feats + (size_t)n * 256;

    if (t < 128) {
        const float* ws0 = Ws0 + (size_t)sp * 64 * 128;
        float f = 0.f;
        #pragma unroll 8
        for (int c = 0; c < 64; ++c) {
            f += (0.25f * accn[c]) * Wd0[c * 128 + t];
            f += nf[c] * ws0[c * 128 + t];
        }
        float sv = f / (1.f + __expf(-f));
        if (t < 64) out[(size_t)n * 256 + t] = sv;
        else        gates[t - 64] = sv;
    }
    __syncthreads();
    if (t < 192) {
        int i = t >> 6;
        int c2 = t & 63;
        const float* ws1 = Ws1 + (size_t)sp * 64 * 64;
        float f = 0.f;
        #pragma unroll 8
        for (int cc = 0; cc < 64; ++cc) {
            f += (0.25f * accn[64 + i * 64 + cc]) * Wd1[cc * 64 + c2];
            f += nf[64 + cc * 3 + i] * ws1[cc * 64 + c2];
        }
        out[(size_t)n * 256 + 64 + c2 * 3 + i] = f * gates[c2];
    }
}

// ---------------------------------------------------------------------------
extern "C" void kernel_launch(void* const* d_in, const int* in_sizes, int n_in,
                              void* d_out, int out_size, void* d_ws, size_t ws_size,
                              hipStream_t stream) {
    const float* vectors     = (const float*)d_in[0];
    const float* node_feats  = (const float*)d_in[1];
    const int*   node_specie = (const int*)d_in[2];
    const int*   senders     = (const int*)d_in[3];
    const int*   receivers   = (const int*)d_in[4];
    const float* W0_up       = (const float*)d_in[5];
    const float* W1_up       = (const float*)d_in[6];
    const float* Wm1         = (const float*)d_in[7];
    const float* Wm2         = (const float*)d_in[8];
    const float* Wm3         = (const float*)d_in[9];
    const float* Ws0         = (const float*)d_in[10];
    const float* Ws1         = (const float*)d_in[11];
    const float* Wd0         = (const float*)d_in[12];
    const float* Wd1         = (const float*)d_in[13];
    float* out = (float*)d_out;

    int E = in_sizes[0] / 3;
    int N = in_sizes[1] / 256;
    int nblk = (N + 1023) / 1024;

    char* wp = (char*)d_ws;
    float* u      = (float*)wp;                 wp += (size_t)N * 256 * 4;
    float* acc    = (float*)wp;                 wp += (size_t)N * 256 * 4;
    uint4* epackA = (uint4*)wp;                 wp += (size_t)(E + 16) * 16;
    float4* epackB = (float4*)wp;               wp += (size_t)(E + 16) * 16;
    short* W1B    = (short*)wp;                 wp += 4 * 512 * 2;
    short* Wm2B   = (short*)wp;                 wp += 8 * 512 * 2;
    short* W3B    = (short*)wp;                 wp += 40 * 512 * 2;
    int*   cnt    = (int*)wp;                   wp += (size_t)N * 4;
    int*   offs   = (int*)wp;                   wp += (size_t)(N + 1) * 4;
    int*   cursor = (int*)wp;                   wp += (size_t)N * 4;
    int*   part   = (int*)wp;                   wp += (size_t)(nblk + 1) * 4;

    hipMemsetAsync(cnt, 0, (size_t)N * sizeof(int), stream);

    prep_kernel<<<13, 256, 0, stream>>>(Wm1, Wm2, Wm3, W1B, Wm2B, W3B);
    hist_kernel<<<1024, 256, 0, stream>>>(receivers, cnt, E);
    scan1_kernel<<<nblk, 256, 0, stream>>>(cnt, offs, part, N);
    scan2_kernel<<<1, 64, 0, stream>>>(part, offs, nblk, N);
    scan3_kernel<<<nblk, 256, 0, stream>>>(offs, cursor, part, N);
    fill_pack_kernel<<<1024, 256, 0, stream>>>(
        vectors, senders, receivers, cursor, epackA, epackB, E);
    node_up_kernel<<<N, 256, 0, stream>>>(node_feats, W0_up, W1_up, u);
    edge_kernel<<<(N + 3) / 4, 256, 0, stream>>>(
        epackA, epackB, offs, (const float4*)u, W1B, Wm2B, W3B, acc, N);
    node_out_kernel<<<N, 256, 0, stream>>>(
        acc, node_feats, node_specie, Wd0, Wd1, Ws0, Ws1, out);
}

// Round 11
// 498.920 us; speedup vs baseline: 1.4335x; 1.0033x over previous
//
#include <hip/hip_runtime.h>
#include <hip/hip_bf16.h>

typedef __attribute__((ext_vector_type(8))) short short8;
typedef __attribute__((ext_vector_type(4))) float f32x4;

__device__ __forceinline__ unsigned bf16u(float x) {
    unsigned u = __float_as_uint(x);
    return (u + 0x7fffu + ((u >> 16) & 1u)) >> 16;
}
__device__ __forceinline__ short bf16s(float x) { return (short)bf16u(x); }

// ---------------------------------------------------------------------------
// Prep: pack Wm1 (8x64), Wm2 (64x64), Wm3 (64x320) into MFMA B-fragment
// layout (bf16). Frag (t,kh): lane l holds B[k=kh*32+(l>>4)*8+i][col=16t+(l&15)].
// ---------------------------------------------------------------------------
__global__ __launch_bounds__(256) void prep_kernel(
    const float* __restrict__ Wm1, const float* __restrict__ Wm2,
    const float* __restrict__ Wm3,
    short* __restrict__ W1B, short* __restrict__ Wm2B, short* __restrict__ W3B)
{
    int idx = blockIdx.x * 256 + threadIdx.x;   // 52 frags * 64 lanes
    if (idx >= 52 * 64) return;
    int l = idx & 63, f = idx >> 6;
    int g = l >> 4, c = l & 15;
    short8 v;
    if (f < 4) {                 // W1B tile t=f: k=i (g==0 only), col=16f+c
        #pragma unroll
        for (int i = 0; i < 8; ++i)
            v[i] = (g == 0) ? bf16s(Wm1[(size_t)i * 64 + f * 16 + c]) : (short)0;
        *(short8*)(W1B + (size_t)f * 512 + l * 8) = v;
    } else if (f < 12) {         // Wm2B
        int f2 = f - 4, t = f2 >> 1, kh = f2 & 1;
        #pragma unroll
        for (int i = 0; i < 8; ++i)
            v[i] = bf16s(Wm2[(size_t)(kh * 32 + g * 8 + i) * 64 + t * 16 + c]);
        *(short8*)(Wm2B + (size_t)f2 * 512 + l * 8) = v;
    } else {                     // W3B
        int f3 = f - 12, t = f3 >> 1, kh = f3 & 1;
        #pragma unroll
        for (int i = 0; i < 8; ++i)
            v[i] = bf16s(Wm3[(size_t)(kh * 32 + g * 8 + i) * 320 + t * 16 + c]);
        *(short8*)(W3B + (size_t)f3 * 512 + l * 8) = v;
    }
}

// ---------------------------------------------------------------------------
// CSR build: histogram -> 3-phase parallel scan -> bucket fill (+ pack)
// ---------------------------------------------------------------------------
__global__ __launch_bounds__(256) void hist_kernel(
    const int* __restrict__ receivers, int* __restrict__ cnt, int E)
{
    int i = blockIdx.x * 256 + threadIdx.x;
    int stride = gridDim.x * 256;
    for (; i < E; i += stride) atomicAdd(&cnt[receivers[i]], 1);
}

// scan1: each block scans 1024 elements (4/thread), writes local-exclusive
// results to offs and block total to part[b].
__global__ __launch_bounds__(256) void scan1_kernel(
    const int* __restrict__ cnt, int* __restrict__ offs,
    int* __restrict__ part, int N)
{
    __shared__ int a_[256], b_[256];
    const int b = blockIdx.x, t = threadIdx.x;
    const int base = b * 1024 + t * 4;
    int v[4];
    #pragma unroll
    for (int k = 0; k < 4; ++k) v[k] = (base + k < N) ? cnt[base + k] : 0;
    int sum = v[0] + v[1] + v[2] + v[3];
    a_[t] = sum;
    __syncthreads();
    int* src = a_; int* dst = b_;
    for (int off = 1; off < 256; off <<= 1) {
        dst[t] = src[t] + ((t >= off) ? src[t - off] : 0);
        __syncthreads();
        int* tmp = src; src = dst; dst = tmp;
    }
    int excl = src[t] - sum;
    if (t == 0) part[b] = src[255];
    int run = excl;
    #pragma unroll
    for (int k = 0; k < 4; ++k) {
        if (base + k < N) offs[base + k] = run;
        run += v[k];
    }
}

// scan2: serial exclusive scan of block partials (nblk small), total -> offs[N]
__global__ void scan2_kernel(int* __restrict__ part, int* __restrict__ offs,
                             int nblk, int N)
{
    if (threadIdx.x == 0 && blockIdx.x == 0) {
        int running = 0;
        for (int i = 0; i < nblk; ++i) {
            int tmp = part[i];
            part[i] = running;
            running += tmp;
        }
        offs[N] = running;
    }
}

// scan3: add block base to offs, mirror into cursor
__global__ __launch_bounds__(256) void scan3_kernel(
    int* __restrict__ offs, int* __restrict__ cursor,
    const int* __restrict__ part, int N)
{
    const int b = blockIdx.x, t = threadIdx.x;
    const int add = part[b];
    const int base = b * 1024 + t * 4;
    #pragma unroll
    for (int k = 0; k < 4; ++k) {
        int i = base + k;
        if (i < N) {
            int o = offs[i] + add;
            offs[i] = o;
            cursor[i] = o;
        }
    }
}

// Scatter per-edge packed record into CSR position:
//  epackA[pos] = basis[0..7] bf16 pairs (MFMA A-fragment data)
//  epackB[pos] = { Yx, Yy, Yz, sender_bits }
__global__ __launch_bounds__(256) void fill_pack_kernel(
    const float* __restrict__ vectors, const int* __restrict__ senders,
    const int* __restrict__ receivers, int* __restrict__ cursor,
    uint4* __restrict__ epackA, float4* __restrict__ epackB, int E)
{
    int i = blockIdx.x * 256 + threadIdx.x;
    int stride = gridDim.x * 256;
    for (; i < E; i += stride) {
        int pos = atomicAdd(&cursor[receivers[i]], 1);
        float vx = vectors[3 * (size_t)i + 0];
        float vy = vectors[3 * (size_t)i + 1];
        float vz = vectors[3 * (size_t)i + 2];
        float r = sqrtf(vx * vx + vy * vy + vz * vz);
        float ir = (r != 0.f) ? 1.f / r : 0.f;
        float ang = r * 0.6283185307179586f;   // pi/5
        float s1, c1;
        __sincosf(ang, &s1, &c1);
        float tc = 2.f * c1;
        float sb = s1, sp = 0.f;
        float coef = 0.6324555320336759f * ir;
        unsigned bw[4];
        #pragma unroll
        for (int h = 0; h < 4; ++h) {
            unsigned lo = bf16u(sb * coef);
            float nx = tc * sb - sp; sp = sb; sb = nx;
            unsigned hi = bf16u(sb * coef);
            nx = tc * sb - sp; sp = sb; sb = nx;
            bw[h] = lo | (hi << 16);
        }
        epackA[pos] = make_uint4(bw[0], bw[1], bw[2], bw[3]);
        epackB[pos] = make_float4(vx * ir, vy * ir, vz * ir,
                                  __int_as_float(senders[i]));
    }
}

// ---------------------------------------------------------------------------
// Node up-projection, d-major interleaved output:
// u[n*256 + d*4 + comp], comp 0..3 = {u0, u1x, u1y, u1z}[d]
// -> per-(edge,q) gather in edge_kernel is one float4 per lane.
// ---------------------------------------------------------------------------
__global__ __launch_bounds__(256) void node_up_kernel(
    const float* __restrict__ node_feats, const float* __restrict__ W0_up,
    const float* __restrict__ W1_up, float* __restrict__ u)
{
    int n = blockIdx.x;
    int t = threadIdx.x;
    const float* nf = node_feats + (size_t)n * 256;
    int comp = t >> 6, d = t & 63;
    float f = 0.f;
    if (comp == 0) {
        #pragma unroll 8
        for (int c = 0; c < 64; ++c) f += nf[c] * W0_up[c * 64 + d];
    } else {
        int i = comp - 1;
        #pragma unroll 8
        for (int c = 0; c < 64; ++c) f += nf[64 + c * 3 + i] * W1_up[c * 64 + d];
    }
    u[(size_t)n * 256 + d * 4 + comp] = f;
}

// ---------------------------------------------------------------------------
// Edge kernel v9: wave per receiver node, 16-edge MFMA chunks.
//  - PLAIN __launch_bounds__(256): R4/R9 A/B showed any min-waves hint makes
//    the allocator snap to 128 regs and spill ~900MB/dispatch of scratch.
//    Live set ~150-240 regs gives the SAME 2 waves/SIMD occupancy spill-free.
//  - u gathered as d-major float4: one dwordx4/lane
//  - W3B fragments staged in LDS; ping-pong pipelined q loop
// ---------------------------------------------------------------------------
__global__ __launch_bounds__(256) void edge_kernel(
    const uint4* __restrict__ epackA, const float4* __restrict__ epackB,
    const int* __restrict__ offs, const float4* __restrict__ u4,
    const short* __restrict__ W1B, const short* __restrict__ Wm2B,
    const short* __restrict__ W3B, float* __restrict__ acc, int N)
{
    __shared__ __align__(16) short ldsW3[40 * 512];   // 40KB staged W3B
    __shared__ __align__(16) short ldsH[4][1024];     // per-wave h buffer (swz)
    __shared__ __align__(16) float ldsMeta[4][16][4]; // Y.xyz + sender

    {   // cooperative stage of W3B (2560 short8)
        const short8* src = (const short8*)W3B;
        short8* dst = (short8*)ldsW3;
        for (int i = threadIdx.x; i < 2560; i += 256) dst[i] = src[i];
    }
    __syncthreads();

    const int lane = threadIdx.x & 63;
    const int wv   = threadIdx.x >> 6;
    const int n    = blockIdx.x * 4 + wv;
    if (n >= N) return;
    const int c = lane & 15, g = lane >> 4;

    float a0q[4]  = {0.f, 0.f, 0.f, 0.f};
    float a1xq[4] = {0.f, 0.f, 0.f, 0.f};
    float a1yq[4] = {0.f, 0.f, 0.f, 0.f};
    float a1zq[4] = {0.f, 0.f, 0.f, 0.f};

    const int beg = offs[n], end = offs[n + 1];

    for (int p0 = beg; p0 < end; p0 += 16) {
        const int m = end - p0;

        // ---- prologue: lanes 0-15, one packed record each ----
        short8 basisA = {0, 0, 0, 0, 0, 0, 0, 0};
        if (lane < 16) {
            uint4 ba = epackA[p0 + lane];
            float4 mb = epackB[p0 + lane];
            if (lane >= m) {
                ba = make_uint4(0u, 0u, 0u, 0u);
                mb = make_float4(0.f, 0.f, 0.f, __int_as_float(0));
            }
            union { uint4 u4v; short8 s8; } cv;
            cv.u4v = ba;
            basisA = cv.s8;
            *(float4*)&ldsMeta[wv][lane][0] = mb;
        }

        // ---- per-lane edge meta for its 4 rows ----
        float Yx[4], Yy[4], Yz[4];
        int snd[4];
        #pragma unroll
        for (int i = 0; i < 4; ++i) {
            int row = 4 * g + i;
            float4 mt = *(const float4*)&ldsMeta[wv][row][0];
            Yx[i] = mt.x; Yy[i] = mt.y; Yz[i] = mt.z;
            snd[i] = __float_as_int(mt.w);
        }

#define PFETCH(Q, M0, M1X, M1Y, M1Z)                                        \
        _Pragma("unroll")                                                   \
        for (int i = 0; i < 4; ++i) {                                       \
            float4 mv = u4[(size_t)snd[i] * 64 + 16 * (Q) + c];             \
            M0[i]  = mv.x; M1X[i] = mv.y;                                   \
            M1Y[i] = mv.z; M1Z[i] = mv.w;                                   \
        }

#define COMPQ(Q, M0, M1X, M1Y, M1Z)                                         \
        _Pragma("unroll")                                                   \
        for (int p = 0; p < 5; ++p) {                                       \
            const int t = 4 * p + (Q);                                      \
            f32x4 w = {0.f, 0.f, 0.f, 0.f};                                 \
            short8 b0 = *(const short8*)(ldsW3 + (size_t)(t * 2) * 512 + lane * 8);     \
            short8 b1 = *(const short8*)(ldsW3 + (size_t)(t * 2 + 1) * 512 + lane * 8); \
            w = __builtin_amdgcn_mfma_f32_16x16x32_bf16(h2f0, b0, w, 0, 0, 0);          \
            w = __builtin_amdgcn_mfma_f32_16x16x32_bf16(h2f1, b1, w, 0, 0, 0);          \
            _Pragma("unroll")                                               \
            for (int i = 0; i < 4; ++i) {                                   \
                float wv_ = w[i];                                           \
                if (p == 0) {                                               \
                    a0q[Q] += wv_ * M0[i];                                  \
                } else if (p == 1) {                                        \
                    float tt = wv_ * M0[i];                                 \
                    a1xq[Q] += tt * Yx[i];                                  \
                    a1yq[Q] += tt * Yy[i];                                  \
                    a1zq[Q] += tt * Yz[i];                                  \
                } else if (p == 2) {                                        \
                    a1xq[Q] += wv_ * M1X[i];                                \
                    a1yq[Q] += wv_ * M1Y[i];                                \
                    a1zq[Q] += wv_ * M1Z[i];                                \
                } else if (p == 3) {                                        \
                    a0q[Q] += wv_ * (M1X[i] * Yx[i] + M1Y[i] * Yy[i] + M1Z[i] * Yz[i]); \
                } else {                                                    \
                    a1xq[Q] += wv_ * (M1Y[i] * Yz[i] - M1Z[i] * Yy[i]);     \
                    a1yq[Q] += wv_ * (M1Z[i] * Yx[i] - M1X[i] * Yz[i]);     \
                    a1zq[Q] += wv_ * (M1X[i] * Yy[i] - M1Y[i] * Yx[i]);     \
                }                                                           \
            }                                                               \
        }

        float m0A[4], m1xA[4], m1yA[4], m1zA[4];
        float m0B[4], m1xB[4], m1yB[4], m1zB[4];
        PFETCH(0, m0A, m1xA, m1yA, m1zA);
        PFETCH(1, m0B, m1xB, m1yB, m1zB);
        __builtin_amdgcn_sched_barrier(0);   // keep gathers issued here

        // ---- layer 1: 4 MFMAs; silu -> ldsH (swizzled bf16) ----
        #pragma unroll
        for (int t = 0; t < 4; ++t) {
            f32x4 h = {0.f, 0.f, 0.f, 0.f};
            short8 bf = *(const short8*)(W1B + (size_t)t * 512 + lane * 8);
            h = __builtin_amdgcn_mfma_f32_16x16x32_bf16(basisA, bf, h, 0, 0, 0);
            #pragma unroll
            for (int i = 0; i < 4; ++i) {
                float x = h[i];
                float h1 = x / (1.f + __expf(-x));
                int row = 4 * g + i;
                ldsH[wv][row * 64 + ((16 * t + c) ^ ((row & 7) << 3))] = bf16s(h1);
            }
        }
        short8 h1f0 = *(const short8*)&ldsH[wv][c * 64 + ((g * 8) ^ ((c & 7) << 3))];
        short8 h1f1 = *(const short8*)&ldsH[wv][c * 64 + ((32 + g * 8) ^ ((c & 7) << 3))];

        // ---- layer 2: 8 MFMAs; silu -> ldsH (reuse) ----
        #pragma unroll
        for (int t = 0; t < 4; ++t) {
            f32x4 h = {0.f, 0.f, 0.f, 0.f};
            short8 b0 = *(const short8*)(Wm2B + (size_t)(t * 2) * 512 + lane * 8);
            short8 b1 = *(const short8*)(Wm2B + (size_t)(t * 2 + 1) * 512 + lane * 8);
            h = __builtin_amdgcn_mfma_f32_16x16x32_bf16(h1f0, b0, h, 0, 0, 0);
            h = __builtin_amdgcn_mfma_f32_16x16x32_bf16(h1f1, b1, h, 0, 0, 0);
            #pragma unroll
            for (int i = 0; i < 4; ++i) {
                float x = h[i];
                float h2 = x / (1.f + __expf(-x));
                int row = 4 * g + i;
                ldsH[wv][row * 64 + ((16 * t + c) ^ ((row & 7) << 3))] = bf16s(h2);
            }
        }
        short8 h2f0 = *(const short8*)&ldsH[wv][c * 64 + ((g * 8) ^ ((c & 7) << 3))];
        short8 h2f1 = *(const short8*)&ldsH[wv][c * 64 + ((32 + g * 8) ^ ((c & 7) << 3))];

        // ---- layer 3 + fused messages, ping-pong pipelined over q ----
        COMPQ(0, m0A, m1xA, m1yA, m1zA);
        __builtin_amdgcn_sched_barrier(0);
        PFETCH(2, m0A, m1xA, m1yA, m1zA);
        COMPQ(1, m0B, m1xB, m1yB, m1zB);
        __builtin_amdgcn_sched_barrier(0);
        PFETCH(3, m0B, m1xB, m1yB, m1zB);
        COMPQ(2, m0A, m1xA, m1yA, m1zA);
        __builtin_amdgcn_sched_barrier(0);
        COMPQ(3, m0B, m1xB, m1yB, m1zB);
#undef PFETCH
#undef COMPQ
    }

    // ---- reduce across the 4 g-groups and store ----
    #pragma unroll
    for (int q = 0; q < 4; ++q) {
        a0q[q]  += __shfl_xor(a0q[q], 16);  a0q[q]  += __shfl_xor(a0q[q], 32);
        a1xq[q] += __shfl_xor(a1xq[q], 16); a1xq[q] += __shfl_xor(a1xq[q], 32);
        a1yq[q] += __shfl_xor(a1yq[q], 16); a1yq[q] += __shfl_xor(a1yq[q], 32);
        a1zq[q] += __shfl_xor(a1zq[q], 16); a1zq[q] += __shfl_xor(a1zq[q], 32);
    }
    if (lane < 16) {
        float* ar = acc + (size_t)n * 256;
        #pragma unroll
        for (int q = 0; q < 4; ++q) {
            ar[16 * q + lane]       = a0q[q];
            ar[64 + 16 * q + lane]  = a1xq[q];
            ar[128 + 16 * q + lane] = a1yq[q];
            ar[192 + 16 * q + lane] = a1zq[q];
        }
    }
}

// ---------------------------------------------------------------------------
// Node epilogue
// ---------------------------------------------------------------------------
__global__ __launch_bounds__(256) void node_out_kernel(
    const float* __restrict__ acc, const float* __restrict__ node_feats,
    const int* __restrict__ node_specie,
    const float* __restrict__ Wd0, const float* __restrict__ Wd1,
    const float* __restrict__ Ws0, const float* __restrict__ Ws1,
    float* __restrict__ out)
{
    int n = blockIdx.x;
    int t = threadIdx.x;
    __shared__ float gates[64];
    int sp = node_specie[n];
    const float* accn = acc + (size_t)n * 256;
    const float* nf = node_feats + (size_t)n * 256;

    if (t < 128) {
        const float* ws0 = Ws0 + (size_t)sp * 64 * 128;
        float f = 0.f;
        #pragma unroll 8
        for (int c = 0; c < 64; ++c) {
            f += (0.25f * accn[c]) * Wd0[c * 128 + t];
            f += nf[c] * ws0[c * 128 + t];
        }
        float sv = f / (1.f + __expf(-f));
        if (t < 64) out[(size_t)n * 256 + t] = sv;
        else        gates[t - 64] = sv;
    }
    __syncthreads();
    if (t < 192) {
        int i = t >> 6;
        int c2 = t & 63;
        const float* ws1 = Ws1 + (size_t)sp * 64 * 64;
        float f = 0.f;
        #pragma unroll 8
        for (int cc = 0; cc < 64; ++cc) {
            f += (0.25f * accn[64 + i * 64 + cc]) * Wd1[cc * 64 + c2];
            f += nf[64 + cc * 3 + i] * ws1[cc * 64 + c2];
        }
        out[(size_t)n * 256 + 64 + c2 * 3 + i] = f * gates[c2];
    }
}

// ---------------------------------------------------------------------------
extern "C" void kernel_launch(void* const* d_in, const int* in_sizes, int n_in,
                              void* d_out, int out_size, void* d_ws, size_t ws_size,
                              hipStream_t stream) {
    const float* vectors     = (const float*)d_in[0];
    const float* node_feats  = (const float*)d_in[1];
    const int*   node_specie = (const int*)d_in[2];
    const int*   senders     = (const int*)d_in[3];
    const int*   receivers   = (const int*)d_in[4];
    const float* W0_up       = (const float*)d_in[5];
    const float* W1_up       = (const float*)d_in[6];
    const float* Wm1         = (const float*)d_in[7];
    const float* Wm2         = (const float*)d_in[8];
    const float* Wm3         = (const float*)d_in[9];
    const float* Ws0         = (const float*)d_in[10];
    const float* Ws1         = (const float*)d_in[11];
    const float* Wd0         = (const float*)d_in[12];
    const float* Wd1         = (const float*)d_in[13];
    float* out = (float*)d_out;

    int E = in_sizes[0] / 3;
    int N = in_sizes[1] / 256;
    int nblk = (N + 1023) / 1024;

    char* wp = (char*)d_ws;
    float* u      = (float*)wp;                 wp += (size_t)N * 256 * 4;
    float* acc    = (float*)wp;                 wp += (size_t)N * 256 * 4;
    uint4* epackA = (uint4*)wp;                 wp += (size_t)(E + 16) * 16;
    float4* epackB = (float4*)wp;               wp += (size_t)(E + 16) * 16;
    short* W1B    = (short*)wp;                 wp += 4 * 512 * 2;
    short* Wm2B   = (short*)wp;                 wp += 8 * 512 * 2;
    short* W3B    = (short*)wp;                 wp += 40 * 512 * 2;
    int*   cnt    = (int*)wp;                   wp += (size_t)N * 4;
    int*   offs   = (int*)wp;                   wp += (size_t)(N + 1) * 4;
    int*   cursor = (int*)wp;                   wp += (size_t)N * 4;
    int*   part   = (int*)wp;                   wp += (size_t)(nblk + 1) * 4;

    hipMemsetAsync(cnt, 0, (size_t)N * sizeof(int), stream);

    prep_kernel<<<13, 256, 0, stream>>>(Wm1, Wm2, Wm3, W1B, Wm2B, W3B);
    hist_kernel<<<1024, 256, 0, stream>>>(receivers, cnt, E);
    scan1_kernel<<<nblk, 256, 0, stream>>>(cnt, offs, part, N);
    scan2_kernel<<<1, 64, 0, stream>>>(part, offs, nblk, N);
    scan3_kernel<<<nblk, 256, 0, stream>>>(offs, cursor, part, N);
    fill_pack_kernel<<<1024, 256, 0, stream>>>(
        vectors, senders, receivers, cursor, epackA, epackB, E);
    node_up_kernel<<<N, 256, 0, stream>>>(node_feats, W0_up, W1_up, u);
    edge_kernel<<<(N + 3) / 4, 256, 0, stream>>>(
        epackA, epackB, offs, (const float4*)u, W1B, Wm2B, W3B, acc, N);
    node_out_kernel<<<N, 256, 0, stream>>>(
        acc, node_feats, node_specie, Wd0, Wd1, Ws0, Ws1, out);
}

// Round 12
// 395.034 us; speedup vs baseline: 1.8104x; 1.2630x over previous
//
#include <hip/hip_runtime.h>
#include <hip/hip_bf16.h>

typedef __attribute__((ext_vector_type(8))) short short8;
typedef __attribute__((ext_vector_type(4))) float f32x4;

__device__ __forceinline__ unsigned bf16u(float x) {
    unsigned u = __float_as_uint(x);
    return (u + 0x7fffu + ((u >> 16) & 1u)) >> 16;
}
__device__ __forceinline__ short bf16s(float x) { return (short)bf16u(x); }

// ---------------------------------------------------------------------------
// Prep: pack Wm1 (8x64), Wm2 (64x64), Wm3 (64x320) into MFMA B-fragment
// layout (bf16). Frag (t,kh): lane l holds B[k=kh*32+(l>>4)*8+i][col=16t+(l&15)].
// ---------------------------------------------------------------------------
__global__ __launch_bounds__(256) void prep_kernel(
    const float* __restrict__ Wm1, const float* __restrict__ Wm2,
    const float* __restrict__ Wm3,
    short* __restrict__ W1B, short* __restrict__ Wm2B, short* __restrict__ W3B)
{
    int idx = blockIdx.x * 256 + threadIdx.x;   // 52 frags * 64 lanes
    if (idx >= 52 * 64) return;
    int l = idx & 63, f = idx >> 6;
    int g = l >> 4, c = l & 15;
    short8 v;
    if (f < 4) {                 // W1B tile t=f: k=i (g==0 only), col=16f+c
        #pragma unroll
        for (int i = 0; i < 8; ++i)
            v[i] = (g == 0) ? bf16s(Wm1[(size_t)i * 64 + f * 16 + c]) : (short)0;
        *(short8*)(W1B + (size_t)f * 512 + l * 8) = v;
    } else if (f < 12) {         // Wm2B
        int f2 = f - 4, t = f2 >> 1, kh = f2 & 1;
        #pragma unroll
        for (int i = 0; i < 8; ++i)
            v[i] = bf16s(Wm2[(size_t)(kh * 32 + g * 8 + i) * 64 + t * 16 + c]);
        *(short8*)(Wm2B + (size_t)f2 * 512 + l * 8) = v;
    } else {                     // W3B
        int f3 = f - 12, t = f3 >> 1, kh = f3 & 1;
        #pragma unroll
        for (int i = 0; i < 8; ++i)
            v[i] = bf16s(Wm3[(size_t)(kh * 32 + g * 8 + i) * 320 + t * 16 + c]);
        *(short8*)(W3B + (size_t)f3 * 512 + l * 8) = v;
    }
}

// ---------------------------------------------------------------------------
// CSR build: histogram -> 3-phase parallel scan -> bucket fill (+ pack)
// ---------------------------------------------------------------------------
__global__ __launch_bounds__(256) void hist_kernel(
    const int* __restrict__ receivers, int* __restrict__ cnt, int E)
{
    int i = blockIdx.x * 256 + threadIdx.x;
    int stride = gridDim.x * 256;
    for (; i < E; i += stride) atomicAdd(&cnt[receivers[i]], 1);
}

__global__ __launch_bounds__(256) void scan1_kernel(
    const int* __restrict__ cnt, int* __restrict__ offs,
    int* __restrict__ part, int N)
{
    __shared__ int a_[256], b_[256];
    const int b = blockIdx.x, t = threadIdx.x;
    const int base = b * 1024 + t * 4;
    int v[4];
    #pragma unroll
    for (int k = 0; k < 4; ++k) v[k] = (base + k < N) ? cnt[base + k] : 0;
    int sum = v[0] + v[1] + v[2] + v[3];
    a_[t] = sum;
    __syncthreads();
    int* src = a_; int* dst = b_;
    for (int off = 1; off < 256; off <<= 1) {
        dst[t] = src[t] + ((t >= off) ? src[t - off] : 0);
        __syncthreads();
        int* tmp = src; src = dst; dst = tmp;
    }
    int excl = src[t] - sum;
    if (t == 0) part[b] = src[255];
    int run = excl;
    #pragma unroll
    for (int k = 0; k < 4; ++k) {
        if (base + k < N) offs[base + k] = run;
        run += v[k];
    }
}

__global__ void scan2_kernel(int* __restrict__ part, int* __restrict__ offs,
                             int nblk, int N)
{
    if (threadIdx.x == 0 && blockIdx.x == 0) {
        int running = 0;
        for (int i = 0; i < nblk; ++i) {
            int tmp = part[i];
            part[i] = running;
            running += tmp;
        }
        offs[N] = running;
    }
}

__global__ __launch_bounds__(256) void scan3_kernel(
    int* __restrict__ offs, int* __restrict__ cursor,
    const int* __restrict__ part, int N)
{
    const int b = blockIdx.x, t = threadIdx.x;
    const int add = part[b];
    const int base = b * 1024 + t * 4;
    #pragma unroll
    for (int k = 0; k < 4; ++k) {
        int i = base + k;
        if (i < N) {
            int o = offs[i] + add;
            offs[i] = o;
            cursor[i] = o;
        }
    }
}

// Scatter per-edge packed record into CSR position.
__global__ __launch_bounds__(256) void fill_pack_kernel(
    const float* __restrict__ vectors, const int* __restrict__ senders,
    const int* __restrict__ receivers, int* __restrict__ cursor,
    uint4* __restrict__ epackA, float4* __restrict__ epackB, int E)
{
    int i = blockIdx.x * 256 + threadIdx.x;
    int stride = gridDim.x * 256;
    for (; i < E; i += stride) {
        int pos = atomicAdd(&cursor[receivers[i]], 1);
        float vx = vectors[3 * (size_t)i + 0];
        float vy = vectors[3 * (size_t)i + 1];
        float vz = vectors[3 * (size_t)i + 2];
        float r = sqrtf(vx * vx + vy * vy + vz * vz);
        float ir = (r != 0.f) ? 1.f / r : 0.f;
        float ang = r * 0.6283185307179586f;   // pi/5
        float s1, c1;
        __sincosf(ang, &s1, &c1);
        float tc = 2.f * c1;
        float sb = s1, sp = 0.f;
        float coef = 0.6324555320336759f * ir;
        unsigned bw[4];
        #pragma unroll
        for (int h = 0; h < 4; ++h) {
            unsigned lo = bf16u(sb * coef);
            float nx = tc * sb - sp; sp = sb; sb = nx;
            unsigned hi = bf16u(sb * coef);
            nx = tc * sb - sp; sp = sb; sb = nx;
            bw[h] = lo | (hi << 16);
        }
        epackA[pos] = make_uint4(bw[0], bw[1], bw[2], bw[3]);
        epackB[pos] = make_float4(vx * ir, vy * ir, vz * ir,
                                  __int_as_float(senders[i]));
    }
}

// ---------------------------------------------------------------------------
// Node up-projection, packed bf16x4 per (node, d):
// ubf[n*64+d] = { bf16(u0)|bf16(u1x)<<16 , bf16(u1y)|bf16(u1z)<<16 }
// Per (edge,q) gather in edge_kernel: one 8B uint2 per lane.
// ---------------------------------------------------------------------------
__global__ __launch_bounds__(256) void node_up_kernel(
    const float* __restrict__ node_feats, const float* __restrict__ W0_up,
    const float* __restrict__ W1_up, uint2* __restrict__ ubf, int N)
{
    int nb = blockIdx.x * 4 + (threadIdx.x >> 6);
    int d  = threadIdx.x & 63;
    if (nb >= N) return;
    const float* nf = node_feats + (size_t)nb * 256;
    float a0 = 0.f, ax = 0.f, ay = 0.f, az = 0.f;
    #pragma unroll 4
    for (int cc = 0; cc < 64; ++cc) {
        float w0 = W0_up[cc * 64 + d];
        float w1 = W1_up[cc * 64 + d];
        a0 += nf[cc] * w0;
        ax += nf[64 + cc * 3 + 0] * w1;
        ay += nf[64 + cc * 3 + 1] * w1;
        az += nf[64 + cc * 3 + 2] * w1;
    }
    ubf[(size_t)nb * 64 + d] = make_uint2(bf16u(a0) | (bf16u(ax) << 16),
                                          bf16u(ay) | (bf16u(az) << 16));
}

// ---------------------------------------------------------------------------
// Edge kernel v10: PERSISTENT wave-per-node, 16-edge MFMA chunks.
//  - 512 blocks; each wave strides over nodes: W3B staged once per block,
//    no block turnover, steady wave supply.
//  - u gathered as packed bf16x4 (uint2, 8B/lane): half the gather bytes of
//    R11 and half the m-register state (raw uint2 held, unpack deferred
//    into COMPQ so the prefetch isn't stalled by an early waitcnt).
//  - plain __launch_bounds__(256): R4/R9/R11 A/B showed min-waves hints
//    force allocator spills (~900MB/dispatch).
// ---------------------------------------------------------------------------
__global__ __launch_bounds__(256) void edge_kernel(
    const uint4* __restrict__ epackA, const float4* __restrict__ epackB,
    const int* __restrict__ offs, const uint2* __restrict__ ubf,
    const short* __restrict__ W1B, const short* __restrict__ Wm2B,
    const short* __restrict__ W3B, float* __restrict__ acc,
    int N, int nwaves)
{
    __shared__ __align__(16) short ldsW3[40 * 512];   // 40KB staged W3B
    __shared__ __align__(16) short ldsH[4][1024];     // per-wave h buffer (swz)
    __shared__ __align__(16) float ldsMeta[4][16][4]; // Y.xyz + sender

    {   // cooperative stage of W3B (2560 short8), once per block
        const short8* src = (const short8*)W3B;
        short8* dst = (short8*)ldsW3;
        for (int i = threadIdx.x; i < 2560; i += 256) dst[i] = src[i];
    }
    __syncthreads();

    const int lane = threadIdx.x & 63;
    const int wv   = threadIdx.x >> 6;
    const int gw   = blockIdx.x * 4 + wv;
    const int c = lane & 15, g = lane >> 4;

    for (int n = gw; n < N; n += nwaves) {

        float a0q[4]  = {0.f, 0.f, 0.f, 0.f};
        float a1xq[4] = {0.f, 0.f, 0.f, 0.f};
        float a1yq[4] = {0.f, 0.f, 0.f, 0.f};
        float a1zq[4] = {0.f, 0.f, 0.f, 0.f};

        const int beg = offs[n], end = offs[n + 1];

        for (int p0 = beg; p0 < end; p0 += 16) {
            const int m = end - p0;

            // ---- prologue: lanes 0-15, one packed record each ----
            short8 basisA = {0, 0, 0, 0, 0, 0, 0, 0};
            if (lane < 16) {
                uint4 ba = epackA[p0 + lane];
                float4 mb = epackB[p0 + lane];
                if (lane >= m) {
                    ba = make_uint4(0u, 0u, 0u, 0u);
                    mb = make_float4(0.f, 0.f, 0.f, __int_as_float(0));
                }
                union { uint4 u4v; short8 s8; } cv;
                cv.u4v = ba;
                basisA = cv.s8;
                *(float4*)&ldsMeta[wv][lane][0] = mb;
            }

            // ---- per-lane edge meta for its 4 rows ----
            float Yx[4], Yy[4], Yz[4];
            int snd[4];
            #pragma unroll
            for (int i = 0; i < 4; ++i) {
                int row = 4 * g + i;
                float4 mt = *(const float4*)&ldsMeta[wv][row][0];
                Yx[i] = mt.x; Yy[i] = mt.y; Yz[i] = mt.z;
                snd[i] = __float_as_int(mt.w);
            }

#define PFETCH(Q, MV)                                                       \
            _Pragma("unroll")                                               \
            for (int i = 0; i < 4; ++i)                                     \
                MV[i] = ubf[(size_t)snd[i] * 64 + 16 * (Q) + c];

#define COMPQ(Q, MV)                                                        \
        {                                                                   \
            float M0[4], M1X[4], M1Y[4], M1Z[4];                            \
            _Pragma("unroll")                                               \
            for (int i = 0; i < 4; ++i) {                                   \
                M0[i]  = __uint_as_float(MV[i].x << 16);                    \
                M1X[i] = __uint_as_float(MV[i].x & 0xffff0000u);            \
                M1Y[i] = __uint_as_float(MV[i].y << 16);                    \
                M1Z[i] = __uint_as_float(MV[i].y & 0xffff0000u);            \
            }                                                               \
            _Pragma("unroll")                                               \
            for (int p = 0; p < 5; ++p) {                                   \
                const int t = 4 * p + (Q);                                  \
                f32x4 w = {0.f, 0.f, 0.f, 0.f};                             \
                short8 b0 = *(const short8*)(ldsW3 + (size_t)(t * 2) * 512 + lane * 8);     \
                short8 b1 = *(const short8*)(ldsW3 + (size_t)(t * 2 + 1) * 512 + lane * 8); \
                w = __builtin_amdgcn_mfma_f32_16x16x32_bf16(h2f0, b0, w, 0, 0, 0);          \
                w = __builtin_amdgcn_mfma_f32_16x16x32_bf16(h2f1, b1, w, 0, 0, 0);          \
                _Pragma("unroll")                                           \
                for (int i = 0; i < 4; ++i) {                               \
                    float wv_ = w[i];                                       \
                    if (p == 0) {                                           \
                        a0q[Q] += wv_ * M0[i];                              \
                    } else if (p == 1) {                                    \
                        float tt = wv_ * M0[i];                             \
                        a1xq[Q] += tt * Yx[i];                              \
                        a1yq[Q] += tt * Yy[i];                              \
                        a1zq[Q] += tt * Yz[i];                              \
                    } else if (p == 2) {                                    \
                        a1xq[Q] += wv_ * M1X[i];                            \
                        a1yq[Q] += wv_ * M1Y[i];                            \
                        a1zq[Q] += wv_ * M1Z[i];                            \
                    } else if (p == 3) {                                    \
                        a0q[Q] += wv_ * (M1X[i] * Yx[i] + M1Y[i] * Yy[i] + M1Z[i] * Yz[i]); \
                    } else {                                                \
                        a1xq[Q] += wv_ * (M1Y[i] * Yz[i] - M1Z[i] * Yy[i]); \
                        a1yq[Q] += wv_ * (M1Z[i] * Yx[i] - M1X[i] * Yz[i]); \
                        a1zq[Q] += wv_ * (M1X[i] * Yy[i] - M1Y[i] * Yx[i]); \
                    }                                                       \
                }                                                           \
            }                                                               \
        }

            uint2 mA[4], mB[4];
            PFETCH(0, mA);
            PFETCH(1, mB);
            __builtin_amdgcn_sched_barrier(0);   // keep gathers issued here

            // ---- layer 1: 4 MFMAs; silu -> ldsH (swizzled bf16) ----
            #pragma unroll
            for (int t = 0; t < 4; ++t) {
                f32x4 h = {0.f, 0.f, 0.f, 0.f};
                short8 bf = *(const short8*)(W1B + (size_t)t * 512 + lane * 8);
                h = __builtin_amdgcn_mfma_f32_16x16x32_bf16(basisA, bf, h, 0, 0, 0);
                #pragma unroll
                for (int i = 0; i < 4; ++i) {
                    float x = h[i];
                    float h1 = x / (1.f + __expf(-x));
                    int row = 4 * g + i;
                    ldsH[wv][row * 64 + ((16 * t + c) ^ ((row & 7) << 3))] = bf16s(h1);
                }
            }
            short8 h1f0 = *(const short8*)&ldsH[wv][c * 64 + ((g * 8) ^ ((c & 7) << 3))];
            short8 h1f1 = *(const short8*)&ldsH[wv][c * 64 + ((32 + g * 8) ^ ((c & 7) << 3))];

            // ---- layer 2: 8 MFMAs; silu -> ldsH (reuse) ----
            #pragma unroll
            for (int t = 0; t < 4; ++t) {
                f32x4 h = {0.f, 0.f, 0.f, 0.f};
                short8 b0 = *(const short8*)(Wm2B + (size_t)(t * 2) * 512 + lane * 8);
                short8 b1 = *(const short8*)(Wm2B + (size_t)(t * 2 + 1) * 512 + lane * 8);
                h = __builtin_amdgcn_mfma_f32_16x16x32_bf16(h1f0, b0, h, 0, 0, 0);
                h = __builtin_amdgcn_mfma_f32_16x16x32_bf16(h1f1, b1, h, 0, 0, 0);
                #pragma unroll
                for (int i = 0; i < 4; ++i) {
                    float x = h[i];
                    float h2 = x / (1.f + __expf(-x));
                    int row = 4 * g + i;
                    ldsH[wv][row * 64 + ((16 * t + c) ^ ((row & 7) << 3))] = bf16s(h2);
                }
            }
            short8 h2f0 = *(const short8*)&ldsH[wv][c * 64 + ((g * 8) ^ ((c & 7) << 3))];
            short8 h2f1 = *(const short8*)&ldsH[wv][c * 64 + ((32 + g * 8) ^ ((c & 7) << 3))];

            // ---- layer 3 + fused messages, ping-pong pipelined over q ----
            COMPQ(0, mA);
            __builtin_amdgcn_sched_barrier(0);
            PFETCH(2, mA);
            COMPQ(1, mB);
            __builtin_amdgcn_sched_barrier(0);
            PFETCH(3, mB);
            COMPQ(2, mA);
            __builtin_amdgcn_sched_barrier(0);
            COMPQ(3, mB);
#undef PFETCH
#undef COMPQ
        }

        // ---- reduce across the 4 g-groups and store ----
        #pragma unroll
        for (int q = 0; q < 4; ++q) {
            a0q[q]  += __shfl_xor(a0q[q], 16);  a0q[q]  += __shfl_xor(a0q[q], 32);
            a1xq[q] += __shfl_xor(a1xq[q], 16); a1xq[q] += __shfl_xor(a1xq[q], 32);
            a1yq[q] += __shfl_xor(a1yq[q], 16); a1yq[q] += __shfl_xor(a1yq[q], 32);
            a1zq[q] += __shfl_xor(a1zq[q], 16); a1zq[q] += __shfl_xor(a1zq[q], 32);
        }
        if (lane < 16) {
            float* ar = acc + (size_t)n * 256;
            #pragma unroll
            for (int q = 0; q < 4; ++q) {
                ar[16 * q + lane]       = a0q[q];
                ar[64 + 16 * q + lane]  = a1xq[q];
                ar[128 + 16 * q + lane] = a1yq[q];
                ar[192 + 16 * q + lane] = a1zq[q];
            }
        }
    }
}

// ---------------------------------------------------------------------------
// Node epilogue
// ---------------------------------------------------------------------------
__global__ __launch_bounds__(256) void node_out_kernel(
    const float* __restrict__ acc, const float* __restrict__ node_feats,
    const int* __restrict__ node_specie,
    const float* __restrict__ Wd0, const float* __restrict__ Wd1,
    const float* __restrict__ Ws0, const float* __restrict__ Ws1,
    float* __restrict__ out)
{
    int n = blockIdx.x;
    int t = threadIdx.x;
    __shared__ float gates[64];
    int sp = node_specie[n];
    const float* accn = acc + (size_t)n * 256;
    const float* nf = node_feats + (size_t)n * 256;

    if (t < 128) {
        const float* ws0 = Ws0 + (size_t)sp * 64 * 128;
        float f = 0.f;
        #pragma unroll 8
        for (int c = 0; c < 64; ++c) {
            f += (0.25f * accn[c]) * Wd0[c * 128 + t];
            f += nf[c] * ws0[c * 128 + t];
        }
        float sv = f / (1.f + __expf(-f));
        if (t < 64) out[(size_t)n * 256 + t] = sv;
        else        gates[t - 64] = sv;
    }
    __syncthreads();
    if (t < 192) {
        int i = t >> 6;
        int c2 = t & 63;
        const float* ws1 = Ws1 + (size_t)sp * 64 * 64;
        float f = 0.f;
        #pragma unroll 8
        for (int cc = 0; cc < 64; ++cc) {
            f += (0.25f * accn[64 + i * 64 + cc]) * Wd1[cc * 64 + c2];
            f += nf[64 + cc * 3 + i] * ws1[cc * 64 + c2];
        }
        out[(size_t)n * 256 + 64 + c2 * 3 + i] = f * gates[c2];
    }
}

// ---------------------------------------------------------------------------
extern "C" void kernel_launch(void* const* d_in, const int* in_sizes, int n_in,
                              void* d_out, int out_size, void* d_ws, size_t ws_size,
                              hipStream_t stream) {
    const float* vectors     = (const float*)d_in[0];
    const float* node_feats  = (const float*)d_in[1];
    const int*   node_specie = (const int*)d_in[2];
    const int*   senders     = (const int*)d_in[3];
    const int*   receivers   = (const int*)d_in[4];
    const float* W0_up       = (const float*)d_in[5];
    const float* W1_up       = (const float*)d_in[6];
    const float* Wm1         = (const float*)d_in[7];
    const float* Wm2         = (const float*)d_in[8];
    const float* Wm3         = (const float*)d_in[9];
    const float* Ws0         = (const float*)d_in[10];
    const float* Ws1         = (const float*)d_in[11];
    const float* Wd0         = (const float*)d_in[12];
    const float* Wd1         = (const float*)d_in[13];
    float* out = (float*)d_out;

    int E = in_sizes[0] / 3;
    int N = in_sizes[1] / 256;
    int nblk = (N + 1023) / 1024;

    char* wp = (char*)d_ws;
    uint2* ubf    = (uint2*)wp;                 wp += (size_t)N * 64 * 8;
    float* acc    = (float*)wp;                 wp += (size_t)N * 256 * 4;
    uint4* epackA = (uint4*)wp;                 wp += (size_t)(E + 16) * 16;
    float4* epackB = (float4*)wp;               wp += (size_t)(E + 16) * 16;
    short* W1B    = (short*)wp;                 wp += 4 * 512 * 2;
    short* Wm2B   = (short*)wp;                 wp += 8 * 512 * 2;
    short* W3B    = (short*)wp;                 wp += 40 * 512 * 2;
    int*   cnt    = (int*)wp;                   wp += (size_t)N * 4;
    int*   offs   = (int*)wp;                   wp += (size_t)(N + 1) * 4;
    int*   cursor = (int*)wp;                   wp += (size_t)N * 4;
    int*   part   = (int*)wp;                   wp += (size_t)(nblk + 1) * 4;

    hipMemsetAsync(cnt, 0, (size_t)N * sizeof(int), stream);

    prep_kernel<<<13, 256, 0, stream>>>(Wm1, Wm2, Wm3, W1B, Wm2B, W3B);
    hist_kernel<<<1024, 256, 0, stream>>>(receivers, cnt, E);
    scan1_kernel<<<nblk, 256, 0, stream>>>(cnt, offs, part, N);
    scan2_kernel<<<1, 64, 0, stream>>>(part, offs, nblk, N);
    scan3_kernel<<<nblk, 256, 0, stream>>>(offs, cursor, part, N);
    fill_pack_kernel<<<1024, 256, 0, stream>>>(
        vectors, senders, receivers, cursor, epackA, epackB, E);
    node_up_kernel<<<(N + 3) / 4, 256, 0, stream>>>(
        node_feats, W0_up, W1_up, ubf, N);
    const int EDGE_BLOCKS = 512;
    edge_kernel<<<EDGE_BLOCKS, 256, 0, stream>>>(
        epackA, epackB, offs, ubf, W1B, Wm2B, W3B, acc, N, EDGE_BLOCKS * 4);
    node_out_kernel<<<N, 256, 0, stream>>>(
        acc, node_feats, node_specie, Wd0, Wd1, Ws0, Ws1, out);
}

// Round 13
// 275.744 us; speedup vs baseline: 2.5937x; 1.4326x over previous
//
#include <hip/hip_runtime.h>
#include <hip/hip_bf16.h>

typedef __attribute__((ext_vector_type(8))) short short8;
typedef __attribute__((ext_vector_type(4))) float f32x4;

__device__ __forceinline__ unsigned bf16u(float x) {
    unsigned u = __float_as_uint(x);
    return (u + 0x7fffu + ((u >> 16) & 1u)) >> 16;
}
__device__ __forceinline__ short bf16s(float x) { return (short)bf16u(x); }

// ---------------------------------------------------------------------------
// Prep: pack Wm1 (8x64), Wm2 (64x64), Wm3 (64x320) into MFMA B-fragment
// layout (bf16). Frag (t,kh): lane l holds B[k=kh*32+(l>>4)*8+i][col=16t+(l&15)].
// ---------------------------------------------------------------------------
__global__ __launch_bounds__(256) void prep_kernel(
    const float* __restrict__ Wm1, const float* __restrict__ Wm2,
    const float* __restrict__ Wm3,
    short* __restrict__ W1B, short* __restrict__ Wm2B, short* __restrict__ W3B)
{
    int idx = blockIdx.x * 256 + threadIdx.x;   // 52 frags * 64 lanes
    if (idx >= 52 * 64) return;
    int l = idx & 63, f = idx >> 6;
    int g = l >> 4, c = l & 15;
    short8 v;
    if (f < 4) {                 // W1B tile t=f: k=i (g==0 only), col=16f+c
        #pragma unroll
        for (int i = 0; i < 8; ++i)
            v[i] = (g == 0) ? bf16s(Wm1[(size_t)i * 64 + f * 16 + c]) : (short)0;
        *(short8*)(W1B + (size_t)f * 512 + l * 8) = v;
    } else if (f < 12) {         // Wm2B
        int f2 = f - 4, t = f2 >> 1, kh = f2 & 1;
        #pragma unroll
        for (int i = 0; i < 8; ++i)
            v[i] = bf16s(Wm2[(size_t)(kh * 32 + g * 8 + i) * 64 + t * 16 + c]);
        *(short8*)(Wm2B + (size_t)f2 * 512 + l * 8) = v;
    } else {                     // W3B
        int f3 = f - 12, t = f3 >> 1, kh = f3 & 1;
        #pragma unroll
        for (int i = 0; i < 8; ++i)
            v[i] = bf16s(Wm3[(size_t)(kh * 32 + g * 8 + i) * 320 + t * 16 + c]);
        *(short8*)(W3B + (size_t)f3 * 512 + l * 8) = v;
    }
}

// ---------------------------------------------------------------------------
// Prep2: pack epilogue weights into B-fragments (bf16):
//  WoB frags: [Wd0 16 | Ws0 5x16 | Wd1 8 | Ws1 5x8] = 144 frags x 512 shorts
// ---------------------------------------------------------------------------
__global__ __launch_bounds__(256) void prep2_kernel(
    const float* __restrict__ Wd0, const float* __restrict__ Ws0,
    const float* __restrict__ Wd1, const float* __restrict__ Ws1,
    short* __restrict__ WoB)
{
    int idx = blockIdx.x * 256 + threadIdx.x;   // 144 frags * 64 lanes
    if (idx >= 144 * 64) return;
    int l = idx & 63, f = idx >> 6;
    int g = l >> 4, c = l & 15;
    short8 v;
    if (f < 16) {
        int t = f >> 1, kh = f & 1;
        #pragma unroll
        for (int i = 0; i < 8; ++i)
            v[i] = bf16s(Wd0[(size_t)(kh * 32 + g * 8 + i) * 128 + t * 16 + c]);
    } else if (f < 96) {
        int s = (f - 16) >> 4, r = (f - 16) & 15, t = r >> 1, kh = r & 1;
        #pragma unroll
        for (int i = 0; i < 8; ++i)
            v[i] = bf16s(Ws0[((size_t)s * 64 + kh * 32 + g * 8 + i) * 128 + t * 16 + c]);
    } else if (f < 104) {
        int r = f - 96, t = r >> 1, kh = r & 1;
        #pragma unroll
        for (int i = 0; i < 8; ++i)
            v[i] = bf16s(Wd1[(size_t)(kh * 32 + g * 8 + i) * 64 + t * 16 + c]);
    } else {
        int s = (f - 104) >> 3, r = (f - 104) & 7, t = r >> 1, kh = r & 1;
        #pragma unroll
        for (int i = 0; i < 8; ++i)
            v[i] = bf16s(Ws1[((size_t)s * 64 + kh * 32 + g * 8 + i) * 64 + t * 16 + c]);
    }
    *(short8*)(WoB + (size_t)f * 512 + l * 8) = v;
}

// ---------------------------------------------------------------------------
// CSR build: histogram -> 3-phase parallel scan -> bucket fill (+ pack)
// ---------------------------------------------------------------------------
__global__ __launch_bounds__(256) void hist_kernel(
    const int* __restrict__ receivers, int* __restrict__ cnt, int E)
{
    int i = blockIdx.x * 256 + threadIdx.x;
    int stride = gridDim.x * 256;
    for (; i < E; i += stride) atomicAdd(&cnt[receivers[i]], 1);
}

__global__ __launch_bounds__(256) void scan1_kernel(
    const int* __restrict__ cnt, int* __restrict__ offs,
    int* __restrict__ part, int N)
{
    __shared__ int a_[256], b_[256];
    const int b = blockIdx.x, t = threadIdx.x;
    const int base = b * 1024 + t * 4;
    int v[4];
    #pragma unroll
    for (int k = 0; k < 4; ++k) v[k] = (base + k < N) ? cnt[base + k] : 0;
    int sum = v[0] + v[1] + v[2] + v[3];
    a_[t] = sum;
    __syncthreads();
    int* src = a_; int* dst = b_;
    for (int off = 1; off < 256; off <<= 1) {
        dst[t] = src[t] + ((t >= off) ? src[t - off] : 0);
        __syncthreads();
        int* tmp = src; src = dst; dst = tmp;
    }
    int excl = src[t] - sum;
    if (t == 0) part[b] = src[255];
    int run = excl;
    #pragma unroll
    for (int k = 0; k < 4; ++k) {
        if (base + k < N) offs[base + k] = run;
        run += v[k];
    }
}

__global__ void scan2_kernel(int* __restrict__ part, int* __restrict__ offs,
                             int nblk, int N)
{
    if (threadIdx.x == 0 && blockIdx.x == 0) {
        int running = 0;
        for (int i = 0; i < nblk; ++i) {
            int tmp = part[i];
            part[i] = running;
            running += tmp;
        }
        offs[N] = running;
    }
}

__global__ __launch_bounds__(256) void scan3_kernel(
    int* __restrict__ offs, int* __restrict__ cursor,
    const int* __restrict__ part, int N)
{
    const int b = blockIdx.x, t = threadIdx.x;
    const int add = part[b];
    const int base = b * 1024 + t * 4;
    #pragma unroll
    for (int k = 0; k < 4; ++k) {
        int i = base + k;
        if (i < N) {
            int o = offs[i] + add;
            offs[i] = o;
            cursor[i] = o;
        }
    }
}

// Scatter per-edge packed record into CSR position.
__global__ __launch_bounds__(256) void fill_pack_kernel(
    const float* __restrict__ vectors, const int* __restrict__ senders,
    const int* __restrict__ receivers, int* __restrict__ cursor,
    uint4* __restrict__ epackA, float4* __restrict__ epackB, int E)
{
    int i = blockIdx.x * 256 + threadIdx.x;
    int stride = gridDim.x * 256;
    for (; i < E; i += stride) {
        int pos = atomicAdd(&cursor[receivers[i]], 1);
        float vx = vectors[3 * (size_t)i + 0];
        float vy = vectors[3 * (size_t)i + 1];
        float vz = vectors[3 * (size_t)i + 2];
        float r = sqrtf(vx * vx + vy * vy + vz * vz);
        float ir = (r != 0.f) ? 1.f / r : 0.f;
        float ang = r * 0.6283185307179586f;   // pi/5
        float s1, c1;
        __sincosf(ang, &s1, &c1);
        float tc = 2.f * c1;
        float sb = s1, sp = 0.f;
        float coef = 0.6324555320336759f * ir;
        unsigned bw[4];
        #pragma unroll
        for (int h = 0; h < 4; ++h) {
            unsigned lo = bf16u(sb * coef);
            float nx = tc * sb - sp; sp = sb; sb = nx;
            unsigned hi = bf16u(sb * coef);
            nx = tc * sb - sp; sp = sb; sb = nx;
            bw[h] = lo | (hi << 16);
        }
        epackA[pos] = make_uint4(bw[0], bw[1], bw[2], bw[3]);
        epackB[pos] = make_float4(vx * ir, vy * ir, vz * ir,
                                  __int_as_float(senders[i]));
    }
}

// ---------------------------------------------------------------------------
// Node up-projection, packed bf16x4 per (node, d):
// ubf[n*64+d] = { bf16(u0)|bf16(u1x)<<16 , bf16(u1y)|bf16(u1z)<<16 }
// Also emits xpk[n][comp][d] bf16 (comp 0 = x0, 1..3 = x1 xyz) for node_out.
// ---------------------------------------------------------------------------
__global__ __launch_bounds__(256) void node_up_kernel(
    const float* __restrict__ node_feats, const float* __restrict__ W0_up,
    const float* __restrict__ W1_up, uint2* __restrict__ ubf,
    short* __restrict__ xpk, int N)
{
    int nb = blockIdx.x * 4 + (threadIdx.x >> 6);
    int d  = threadIdx.x & 63;
    if (nb >= N) return;
    const float* nf = node_feats + (size_t)nb * 256;
    float a0 = 0.f, ax = 0.f, ay = 0.f, az = 0.f;
    #pragma unroll 4
    for (int cc = 0; cc < 64; ++cc) {
        float w0 = W0_up[cc * 64 + d];
        float w1 = W1_up[cc * 64 + d];
        a0 += nf[cc] * w0;
        ax += nf[64 + cc * 3 + 0] * w1;
        ay += nf[64 + cc * 3 + 1] * w1;
        az += nf[64 + cc * 3 + 2] * w1;
    }
    ubf[(size_t)nb * 64 + d] = make_uint2(bf16u(a0) | (bf16u(ax) << 16),
                                          bf16u(ay) | (bf16u(az) << 16));
    short* xp = xpk + (size_t)nb * 256;
    xp[d]       = bf16s(nf[d]);
    xp[64 + d]  = bf16s(nf[64 + d * 3 + 0]);
    xp[128 + d] = bf16s(nf[64 + d * 3 + 1]);
    xp[192 + d] = bf16s(nf[64 + d * 3 + 2]);
}

// ---------------------------------------------------------------------------
// Edge kernel v10: PERSISTENT wave-per-node, 16-edge MFMA chunks. (unchanged)
// ---------------------------------------------------------------------------
__global__ __launch_bounds__(256) void edge_kernel(
    const uint4* __restrict__ epackA, const float4* __restrict__ epackB,
    const int* __restrict__ offs, const uint2* __restrict__ ubf,
    const short* __restrict__ W1B, const short* __restrict__ Wm2B,
    const short* __restrict__ W3B, float* __restrict__ acc,
    int N, int nwaves)
{
    __shared__ __align__(16) short ldsW3[40 * 512];   // 40KB staged W3B
    __shared__ __align__(16) short ldsH[4][1024];     // per-wave h buffer (swz)
    __shared__ __align__(16) float ldsMeta[4][16][4]; // Y.xyz + sender

    {   // cooperative stage of W3B (2560 short8), once per block
        const short8* src = (const short8*)W3B;
        short8* dst = (short8*)ldsW3;
        for (int i = threadIdx.x; i < 2560; i += 256) dst[i] = src[i];
    }
    __syncthreads();

    const int lane = threadIdx.x & 63;
    const int wv   = threadIdx.x >> 6;
    const int gw   = blockIdx.x * 4 + wv;
    const int c = lane & 15, g = lane >> 4;

    for (int n = gw; n < N; n += nwaves) {

        float a0q[4]  = {0.f, 0.f, 0.f, 0.f};
        float a1xq[4] = {0.f, 0.f, 0.f, 0.f};
        float a1yq[4] = {0.f, 0.f, 0.f, 0.f};
        float a1zq[4] = {0.f, 0.f, 0.f, 0.f};

        const int beg = offs[n], end = offs[n + 1];

        for (int p0 = beg; p0 < end; p0 += 16) {
            const int m = end - p0;

            short8 basisA = {0, 0, 0, 0, 0, 0, 0, 0};
            if (lane < 16) {
                uint4 ba = epackA[p0 + lane];
                float4 mb = epackB[p0 + lane];
                if (lane >= m) {
                    ba = make_uint4(0u, 0u, 0u, 0u);
                    mb = make_float4(0.f, 0.f, 0.f, __int_as_float(0));
                }
                union { uint4 u4v; short8 s8; } cv;
                cv.u4v = ba;
                basisA = cv.s8;
                *(float4*)&ldsMeta[wv][lane][0] = mb;
            }

            float Yx[4], Yy[4], Yz[4];
            int snd[4];
            #pragma unroll
            for (int i = 0; i < 4; ++i) {
                int row = 4 * g + i;
                float4 mt = *(const float4*)&ldsMeta[wv][row][0];
                Yx[i] = mt.x; Yy[i] = mt.y; Yz[i] = mt.z;
                snd[i] = __float_as_int(mt.w);
            }

#define PFETCH(Q, MV)                                                       \
            _Pragma("unroll")                                               \
            for (int i = 0; i < 4; ++i)                                     \
                MV[i] = ubf[(size_t)snd[i] * 64 + 16 * (Q) + c];

#define COMPQ(Q, MV)                                                        \
        {                                                                   \
            float M0[4], M1X[4], M1Y[4], M1Z[4];                            \
            _Pragma("unroll")                                               \
            for (int i = 0; i < 4; ++i) {                                   \
                M0[i]  = __uint_as_float(MV[i].x << 16);                    \
                M1X[i] = __uint_as_float(MV[i].x & 0xffff0000u);            \
                M1Y[i] = __uint_as_float(MV[i].y << 16);                    \
                M1Z[i] = __uint_as_float(MV[i].y & 0xffff0000u);            \
            }                                                               \
            _Pragma("unroll")                                               \
            for (int p = 0; p < 5; ++p) {                                   \
                const int t = 4 * p + (Q);                                  \
                f32x4 w = {0.f, 0.f, 0.f, 0.f};                             \
                short8 b0 = *(const short8*)(ldsW3 + (size_t)(t * 2) * 512 + lane * 8);     \
                short8 b1 = *(const short8*)(ldsW3 + (size_t)(t * 2 + 1) * 512 + lane * 8); \
                w = __builtin_amdgcn_mfma_f32_16x16x32_bf16(h2f0, b0, w, 0, 0, 0);          \
                w = __builtin_amdgcn_mfma_f32_16x16x32_bf16(h2f1, b1, w, 0, 0, 0);          \
                _Pragma("unroll")                                           \
                for (int i = 0; i < 4; ++i) {                               \
                    float wv_ = w[i];                                       \
                    if (p == 0) {                                           \
                        a0q[Q] += wv_ * M0[i];                              \
                    } else if (p == 1) {                                    \
                        float tt = wv_ * M0[i];                             \
                        a1xq[Q] += tt * Yx[i];                              \
                        a1yq[Q] += tt * Yy[i];                              \
                        a1zq[Q] += tt * Yz[i];                              \
                    } else if (p == 2) {                                    \
                        a1xq[Q] += wv_ * M1X[i];                            \
                        a1yq[Q] += wv_ * M1Y[i];                            \
                        a1zq[Q] += wv_ * M1Z[i];                            \
                    } else if (p == 3) {                                    \
                        a0q[Q] += wv_ * (M1X[i] * Yx[i] + M1Y[i] * Yy[i] + M1Z[i] * Yz[i]); \
                    } else {                                                \
                        a1xq[Q] += wv_ * (M1Y[i] * Yz[i] - M1Z[i] * Yy[i]); \
                        a1yq[Q] += wv_ * (M1Z[i] * Yx[i] - M1X[i] * Yz[i]); \
                        a1zq[Q] += wv_ * (M1X[i] * Yy[i] - M1Y[i] * Yx[i]); \
                    }                                                       \
                }                                                           \
            }                                                               \
        }

            uint2 mA[4], mB[4];
            PFETCH(0, mA);
            PFETCH(1, mB);
            __builtin_amdgcn_sched_barrier(0);   // keep gathers issued here

            // ---- layer 1: 4 MFMAs; silu -> ldsH (swizzled bf16) ----
            #pragma unroll
            for (int t = 0; t < 4; ++t) {
                f32x4 h = {0.f, 0.f, 0.f, 0.f};
                short8 bf = *(const short8*)(W1B + (size_t)t * 512 + lane * 8);
                h = __builtin_amdgcn_mfma_f32_16x16x32_bf16(basisA, bf, h, 0, 0, 0);
                #pragma unroll
                for (int i = 0; i < 4; ++i) {
                    float x = h[i];
                    float h1 = x / (1.f + __expf(-x));
                    int row = 4 * g + i;
                    ldsH[wv][row * 64 + ((16 * t + c) ^ ((row & 7) << 3))] = bf16s(h1);
                }
            }
            short8 h1f0 = *(const short8*)&ldsH[wv][c * 64 + ((g * 8) ^ ((c & 7) << 3))];
            short8 h1f1 = *(const short8*)&ldsH[wv][c * 64 + ((32 + g * 8) ^ ((c & 7) << 3))];

            // ---- layer 2: 8 MFMAs; silu -> ldsH (reuse) ----
            #pragma unroll
            for (int t = 0; t < 4; ++t) {
                f32x4 h = {0.f, 0.f, 0.f, 0.f};
                short8 b0 = *(const short8*)(Wm2B + (size_t)(t * 2) * 512 + lane * 8);
                short8 b1 = *(const short8*)(Wm2B + (size_t)(t * 2 + 1) * 512 + lane * 8);
                h = __builtin_amdgcn_mfma_f32_16x16x32_bf16(h1f0, b0, h, 0, 0, 0);
                h = __builtin_amdgcn_mfma_f32_16x16x32_bf16(h1f1, b1, h, 0, 0, 0);
                #pragma unroll
                for (int i = 0; i < 4; ++i) {
                    float x = h[i];
                    float h2 = x / (1.f + __expf(-x));
                    int row = 4 * g + i;
                    ldsH[wv][row * 64 + ((16 * t + c) ^ ((row & 7) << 3))] = bf16s(h2);
                }
            }
            short8 h2f0 = *(const short8*)&ldsH[wv][c * 64 + ((g * 8) ^ ((c & 7) << 3))];
            short8 h2f1 = *(const short8*)&ldsH[wv][c * 64 + ((32 + g * 8) ^ ((c & 7) << 3))];

            // ---- layer 3 + fused messages, ping-pong pipelined over q ----
            COMPQ(0, mA);
            __builtin_amdgcn_sched_barrier(0);
            PFETCH(2, mA);
            COMPQ(1, mB);
            __builtin_amdgcn_sched_barrier(0);
            PFETCH(3, mB);
            COMPQ(2, mA);
            __builtin_amdgcn_sched_barrier(0);
            COMPQ(3, mB);
#undef PFETCH
#undef COMPQ
        }

        #pragma unroll
        for (int q = 0; q < 4; ++q) {
            a0q[q]  += __shfl_xor(a0q[q], 16);  a0q[q]  += __shfl_xor(a0q[q], 32);
            a1xq[q] += __shfl_xor(a1xq[q], 16); a1xq[q] += __shfl_xor(a1xq[q], 32);
            a1yq[q] += __shfl_xor(a1yq[q], 16); a1yq[q] += __shfl_xor(a1yq[q], 32);
            a1zq[q] += __shfl_xor(a1zq[q], 16); a1zq[q] += __shfl_xor(a1zq[q], 32);
        }
        if (lane < 16) {
            float* ar = acc + (size_t)n * 256;
            #pragma unroll
            for (int q = 0; q < 4; ++q) {
                ar[16 * q + lane]       = a0q[q];
                ar[64 + 16 * q + lane]  = a1xq[q];
                ar[128 + 16 * q + lane] = a1yq[q];
                ar[192 + 16 * q + lane] = a1zq[q];
            }
        }
    }
}

// ---------------------------------------------------------------------------
// Node epilogue v2: MFMA masked-species dense GEMM.
//  f0 = (0.25*a0)@Wd0 + sum_s (x0 * 1[sp=s]) @ Ws0[s]   (hi/lo split on a0)
//  f1 = (0.25*a1)@Wd1 + sum_s (x1 * 1[sp=s]) @ Ws1[s]
//  One wave = 16 nodes. Gates and f1 land in the same lane -> register mul.
//  Results staged in per-wave LDS rows, written out coalesced float4.
// ---------------------------------------------------------------------------
__global__ __launch_bounds__(256) void node_out_kernel(
    const float* __restrict__ acc, const short* __restrict__ xpk,
    const int* __restrict__ node_specie, const short* __restrict__ WoB,
    float* __restrict__ out, int N)
{
    __shared__ float ldsOut[4][16][256];   // 64KB
    const int lane = threadIdx.x & 63;
    const int wv   = threadIdx.x >> 6;
    const int c = lane & 15, g = lane >> 4;
    const int n0 = (blockIdx.x * 4 + wv) * 16;
    if (n0 >= N) return;

    const int nc = min(n0 + c, N - 1);        // this lane's A-row node
    const int sp_c = node_specie[nc];
    const short8 z8 = {0, 0, 0, 0, 0, 0, 0, 0};

    // ---- A-frags: x0 (bf16 direct), a0 (f32 -> hi/lo bf16, 0.25 folded) ----
    short8 x0f[2], a0hi[2], a0lo[2];
    #pragma unroll
    for (int kh = 0; kh < 2; ++kh) {
        x0f[kh] = *(const short8*)&xpk[(size_t)nc * 256 + kh * 32 + g * 8];
        const float* ap = acc + (size_t)nc * 256 + kh * 32 + g * 8;
        #pragma unroll
        for (int i = 0; i < 8; ++i) {
            float v = 0.25f * ap[i];
            unsigned h = bf16u(v);
            a0hi[kh][i] = (short)h;
            a0lo[kh][i] = (short)bf16u(v - __uint_as_float(h << 16));
        }
    }

    // ---- f0: 8 output tiles ----
    f32x4 w0[8];
    #pragma unroll
    for (int t = 0; t < 8; ++t) w0[t] = (f32x4){0.f, 0.f, 0.f, 0.f};
    #pragma unroll
    for (int t = 0; t < 8; ++t)
        #pragma unroll
        for (int kh = 0; kh < 2; ++kh) {
            short8 b = *(const short8*)(WoB + (size_t)(t * 2 + kh) * 512 + lane * 8);
            w0[t] = __builtin_amdgcn_mfma_f32_16x16x32_bf16(a0hi[kh], b, w0[t], 0, 0, 0);
            w0[t] = __builtin_amdgcn_mfma_f32_16x16x32_bf16(a0lo[kh], b, w0[t], 0, 0, 0);
        }
    #pragma unroll
    for (int s = 0; s < 5; ++s) {
        if (!__any(sp_c == s)) continue;
        short8 mk0 = (sp_c == s) ? x0f[0] : z8;
        short8 mk1 = (sp_c == s) ? x0f[1] : z8;
        #pragma unroll
        for (int t = 0; t < 8; ++t) {
            short8 b0 = *(const short8*)(WoB + (size_t)(16 + s * 16 + t * 2) * 512 + lane * 8);
            short8 b1 = *(const short8*)(WoB + (size_t)(16 + s * 16 + t * 2 + 1) * 512 + lane * 8);
            w0[t] = __builtin_amdgcn_mfma_f32_16x16x32_bf16(mk0, b0, w0[t], 0, 0, 0);
            w0[t] = __builtin_amdgcn_mfma_f32_16x16x32_bf16(mk1, b1, w0[t], 0, 0, 0);
        }
    }
    // silu: t<4 -> scalars (to LDS), t>=4 -> gates (kept in regs)
    float gate[4][4];
    #pragma unroll
    for (int t = 0; t < 8; ++t)
        #pragma unroll
        for (int i = 0; i < 4; ++i) {
            float x = w0[t][i];
            float sv = x / (1.f + __expf(-x));
            if (t < 4) ldsOut[wv][4 * g + i][16 * t + c] = sv;
            else       gate[t - 4][i] = sv;
        }

    // ---- f1: 3 comps x 4 tiles ----
    short8 x1f[3][2], a1hi[3][2], a1lo[3][2];
    #pragma unroll
    for (int j = 0; j < 3; ++j)
        #pragma unroll
        for (int kh = 0; kh < 2; ++kh) {
            x1f[j][kh] = *(const short8*)&xpk[(size_t)nc * 256 + (1 + j) * 64 + kh * 32 + g * 8];
            const float* ap = acc + (size_t)nc * 256 + 64 + 64 * j + kh * 32 + g * 8;
            #pragma unroll
            for (int i = 0; i < 8; ++i) {
                float v = 0.25f * ap[i];
                unsigned h = bf16u(v);
                a1hi[j][kh][i] = (short)h;
                a1lo[j][kh][i] = (short)bf16u(v - __uint_as_float(h << 16));
            }
        }

    f32x4 w1[3][4];
    #pragma unroll
    for (int j = 0; j < 3; ++j)
        #pragma unroll
        for (int t = 0; t < 4; ++t) w1[j][t] = (f32x4){0.f, 0.f, 0.f, 0.f};
    #pragma unroll
    for (int t = 0; t < 4; ++t)
        #pragma unroll
        for (int kh = 0; kh < 2; ++kh) {
            short8 b = *(const short8*)(WoB + (size_t)(96 + t * 2 + kh) * 512 + lane * 8);
            #pragma unroll
            for (int j = 0; j < 3; ++j) {
                w1[j][t] = __builtin_amdgcn_mfma_f32_16x16x32_bf16(a1hi[j][kh], b, w1[j][t], 0, 0, 0);
                w1[j][t] = __builtin_amdgcn_mfma_f32_16x16x32_bf16(a1lo[j][kh], b, w1[j][t], 0, 0, 0);
            }
        }
    #pragma unroll
    for (int s = 0; s < 5; ++s) {
        if (!__any(sp_c == s)) continue;
        short8 m1[3][2];
        #pragma unroll
        for (int j = 0; j < 3; ++j) {
            m1[j][0] = (sp_c == s) ? x1f[j][0] : z8;
            m1[j][1] = (sp_c == s) ? x1f[j][1] : z8;
        }
        #pragma unroll
        for (int t = 0; t < 4; ++t)
            #pragma unroll
            for (int kh = 0; kh < 2; ++kh) {
                short8 b = *(const short8*)(WoB + (size_t)(104 + s * 8 + t * 2 + kh) * 512 + lane * 8);
                #pragma unroll
                for (int j = 0; j < 3; ++j)
                    w1[j][t] = __builtin_amdgcn_mfma_f32_16x16x32_bf16(m1[j][kh], b, w1[j][t], 0, 0, 0);
            }
    }
    // vec = f1 * gate -> LDS (out layout 64 + ch*3 + j, ch = 16t+c)
    #pragma unroll
    for (int j = 0; j < 3; ++j)
        #pragma unroll
        for (int t = 0; t < 4; ++t)
            #pragma unroll
            for (int i = 0; i < 4; ++i)
                ldsOut[wv][4 * g + i][64 + (16 * t + c) * 3 + j] = w1[j][t][i] * gate[t][i];

    // ---- coalesced write-out: 16 rows x 1KB ----
    #pragma unroll 4
    for (int r = 0; r < 16; ++r) {
        int nn = n0 + r;
        if (nn < N)
            *(float4*)&out[(size_t)nn * 256 + lane * 4] =
                *(const float4*)&ldsOut[wv][r][lane * 4];
    }
}

// ---------------------------------------------------------------------------
extern "C" void kernel_launch(void* const* d_in, const int* in_sizes, int n_in,
                              void* d_out, int out_size, void* d_ws, size_t ws_size,
                              hipStream_t stream) {
    const float* vectors     = (const float*)d_in[0];
    const float* node_feats  = (const float*)d_in[1];
    const int*   node_specie = (const int*)d_in[2];
    const int*   senders     = (const int*)d_in[3];
    const int*   receivers   = (const int*)d_in[4];
    const float* W0_up       = (const float*)d_in[5];
    const float* W1_up       = (const float*)d_in[6];
    const float* Wm1         = (const float*)d_in[7];
    const float* Wm2         = (const float*)d_in[8];
    const float* Wm3         = (const float*)d_in[9];
    const float* Ws0         = (const float*)d_in[10];
    const float* Ws1         = (const float*)d_in[11];
    const float* Wd0         = (const float*)d_in[12];
    const float* Wd1         = (const float*)d_in[13];
    float* out = (float*)d_out;

    int E = in_sizes[0] / 3;
    int N = in_sizes[1] / 256;
    int nblk = (N + 1023) / 1024;

    char* wp = (char*)d_ws;
    uint2* ubf    = (uint2*)wp;                 wp += (size_t)N * 64 * 8;
    float* acc    = (float*)wp;                 wp += (size_t)N * 256 * 4;
    short* xpk    = (short*)wp;                 wp += (size_t)N * 256 * 2;
    uint4* epackA = (uint4*)wp;                 wp += (size_t)(E + 16) * 16;
    float4* epackB = (float4*)wp;               wp += (size_t)(E + 16) * 16;
    short* W1B    = (short*)wp;                 wp += 4 * 512 * 2;
    short* Wm2B   = (short*)wp;                 wp += 8 * 512 * 2;
    short* W3B    = (short*)wp;                 wp += 40 * 512 * 2;
    short* WoB    = (short*)wp;                 wp += 144 * 512 * 2;
    int*   cnt    = (int*)wp;                   wp += (size_t)N * 4;
    int*   offs   = (int*)wp;                   wp += (size_t)(N + 1) * 4;
    int*   cursor = (int*)wp;                   wp += (size_t)N * 4;
    int*   part   = (int*)wp;                   wp += (size_t)(nblk + 1) * 4;

    hipMemsetAsync(cnt, 0, (size_t)N * sizeof(int), stream);

    prep_kernel<<<13, 256, 0, stream>>>(Wm1, Wm2, Wm3, W1B, Wm2B, W3B);
    prep2_kernel<<<36, 256, 0, stream>>>(Wd0, Ws0, Wd1, Ws1, WoB);
    hist_kernel<<<1024, 256, 0, stream>>>(receivers, cnt, E);
    scan1_kernel<<<nblk, 256, 0, stream>>>(cnt, offs, part, N);
    scan2_kernel<<<1, 64, 0, stream>>>(part, offs, nblk, N);
    scan3_kernel<<<nblk, 256, 0, stream>>>(offs, cursor, part, N);
    fill_pack_kernel<<<1024, 256, 0, stream>>>(
        vectors, senders, receivers, cursor, epackA, epackB, E);
    node_up_kernel<<<(N + 3) / 4, 256, 0, stream>>>(
        node_feats, W0_up, W1_up, ubf, xpk, N);
    const int EDGE_BLOCKS = 512;
    edge_kernel<<<EDGE_BLOCKS, 256, 0, stream>>>(
        epackA, epackB, offs, ubf, W1B, Wm2B, W3B, acc, N, EDGE_BLOCKS * 4);
    int ngroups = (N + 15) / 16;
    node_out_kernel<<<(ngroups + 3) / 4, 256, 0, stream>>>(
        acc, xpk, node_specie, WoB, out, N);
}